// Round 15
// baseline (421.776 us; speedup 1.0000x reference)
//
#include <hip/hip_runtime.h>
#include <hip/hip_fp16.h>
#include <cstdint>
#include <cstddef>

typedef _Float16 f16;
typedef _Float16 half8 __attribute__((ext_vector_type(8)));
typedef _Float16 half4v __attribute__((ext_vector_type(4)));
typedef float floatx4 __attribute__((ext_vector_type(4)));

#define MTOT 49152  // B*T*HW rows total (=2*96*256), also = N_TOT*T
#define QSCALE 0.180336880111120426f  // 0.125 * log2(e): folds softmax base-2

// ---------------------------------------------------------------------------
// async global->LDS, 16B per lane
__device__ __forceinline__ void gload_lds16(const f16* g, f16* l) {
  __builtin_amdgcn_global_load_lds((const __attribute__((address_space(1))) void*)g,
                                   (__attribute__((address_space(3))) void*)l, 16, 0, 0);
}

// alignment-tolerant 16B load (addr may be only 4B-aligned)
__device__ __forceinline__ half8 load_h8u(const f16* p) {
  half8 v;
  __builtin_memcpy(&v, p, 16);
  return v;
}

// ---------------------------------------------------------------------------
// Convert weights fp32 -> f16. WQKV rows: [0,512)=Wq [512,1024)=Wk
// [1024,1536)=Wkl [1536,2048)=Wvl [2048,2560)=Wv.  WO separate.
__global__ __launch_bounds__(256) void wconv_kernel(
    const float* __restrict__ Wq, const float* __restrict__ Wk,
    const float* __restrict__ Wv, const float* __restrict__ Wkl,
    const float* __restrict__ Wvl, const float* __restrict__ Wo,
    f16* __restrict__ WQKV, f16* __restrict__ WO) {
  int idx = blockIdx.x * 256 + threadIdx.x;
  if (idx < 2560 * 512) {
    int row = idx >> 9;
    int col = idx & 511;
    int seg = row >> 9;
    int r = row & 511;
    const float* src;
    switch (seg) {
      case 0: src = Wq; break;
      case 1: src = Wk; break;
      case 2: src = Wkl; break;
      case 3: src = Wvl; break;
      default: src = Wv; break;
    }
    WQKV[idx] = (f16)src[r * 512 + col];
  }
  if (idx < 512 * 512) WO[idx] = (f16)Wo[idx];
}

// ---------------------------------------------------------------------------
// LayerNorm over D. x layout (B=2, D=512, T=96, HW=256).
// Output XN f16 row-major [m][512], m = (b*256+hw)*96 + t.
// x values register-cached (static unroll) -> single HBM read pass.
__global__ __launch_bounds__(256) void ln_kernel(
    const float* __restrict__ x, const float* __restrict__ gamma,
    const float* __restrict__ beta, f16* __restrict__ XN) {
  const int hwg = blockIdx.x & 3;
  const int t   = (blockIdx.x >> 2) % 96;
  const int b   = blockIdx.x / (4 * 96);
  const int lhw = threadIdx.x & 63;
  const int dg  = threadIdx.x >> 6;
  const int hw  = hwg * 64 + lhw;
  const float* xp = x + (size_t)b * 512 * 24576 + (size_t)t * 256 + hw +
                    (size_t)dg * 128 * 24576;

  float v[128];
  float s = 0.f, s2 = 0.f;
#pragma unroll
  for (int j = 0; j < 128; ++j) {
    float u = xp[(size_t)j * 24576];
    v[j] = u;
    s += u;
    s2 += u * u;
  }
  __shared__ float S1[4][64], S2[4][64];
  S1[dg][lhw] = s;
  S2[dg][lhw] = s2;
  __syncthreads();
  s  = S1[0][lhw] + S1[1][lhw] + S1[2][lhw] + S1[3][lhw];
  s2 = S2[0][lhw] + S2[1][lhw] + S2[2][lhw] + S2[3][lhw];
  const float mean = s * (1.f / 512.f);
  float var = s2 * (1.f / 512.f) - mean * mean;
  var = fmaxf(var, 0.f);
  const float rstd = rsqrtf(var + 1e-6f);
  const int n = b * 256 + hw;
  f16* outp = XN + ((size_t)n * 96 + t) * 512 + dg * 128;
#pragma unroll
  for (int d0 = 0; d0 < 128; d0 += 8) {
    half8 buf;
#pragma unroll
    for (int j = 0; j < 8; ++j) {
      const int d = dg * 128 + d0 + j;
      buf[j] = (f16)((v[d0 + j] - mean) * rstd * gamma[d] + beta[d]);
    }
    *(half8*)(outp + d0) = buf;
  }
}

// ---------------------------------------------------------------------------
// GEMM A (projections): C[m][n] = sum_k A[m][k]*B[n][k], K=512, N=2560.
// 256x256 tile, BK=64, 512 threads = 8 waves (2m x 4n), wave tile 128x64.
// B-FROM-L2: B fragments read directly from global (all 10 B-panels = 2.6MB,
// L2-resident on every XCD), register double-buffered. Only A staged to LDS
// (dbuf 64KB, XOR swizzle T2) -> LDS read traffic per KT halves (24->16
// b128/wave), which was the 30%-MfmaUtil binding constraint.
// 2 phases per KT: pA {ds_read a-mh0, stage Ah1(kt+1), 32 MFMA},
// pB {ds_read a-mh1, BG(kt+1)->reg, 32 MFMA, barrier, stage Ah0(kt+2)->cur,
// vmcnt(10), barrier}. Ledger: at vmcnt, queue = [Ah0(kt+1)2, Ah1(kt+1)2,
// BG(kt+1)8, Ah0(kt+2)2]=14 -> vmcnt(10) waits exactly S(kt+1).
// Epilogue esc scratch aliases LA[0] (disjoint from kt=7's LA[1] reads).
__global__ __launch_bounds__(512, 2) void gemmA_kernel(
    const f16* __restrict__ A, const f16* __restrict__ B,
    f16* __restrict__ Cqkv, const float* __restrict__ qbias) {
  __shared__ f16 LA[2][256 * 64];

  const int lin = blockIdx.x;
  const int cpx = (int)gridDim.x >> 3;
  const int swz = (lin & 7) * cpx + (lin >> 3);
  const int o = ((gridDim.x & 7) == 0) ? swz : lin;  // bijective only if %8==0
  const int mt = o / 10;
  const int nt = o % 10;
  const int m0 = mt * 256;
  const int n0 = nt * 256;

  const int tid = threadIdx.x;
  const int wid = tid >> 6;
  const int lane = tid & 63;
  const int wm = wid >> 2;  // 0..1
  const int wn = wid & 3;   // 0..3
  const int l15 = lane & 15, l4 = lane >> 4;

  // A staging: thread -> (row = tid>>3 [+64j], chunk = tid&7); source chunk
  // pre-XOR by row&7 so LDS stays linear (rule #21)
  const int srow = tid >> 3;
  const int scol = ((tid & 7) ^ (srow & 7)) * 8;
  const f16* Abase = A + (size_t)(m0 + srow) * 512 + scol;

  // per-lane ds_read chunk offsets (row&7 == l15&7 on read side)
  const int cks0 = ((l4) ^ (l15 & 7)) * 8;
  const int cks1 = ((4 + l4) ^ (l15 & 7)) * 8;
  const int arow = wm * 128 + l15;

  // B global fragment base: row n0+wn*64+l15 (+nf*16 rows), k = kt*64+ks*32+l4*8
  const f16* bgp = B + (size_t)(n0 + wn * 64 + l15) * 512 + l4 * 8;

  floatx4 acc[8][4] = {};
  half8 a_f[4][2];
  half8 b_f[2][4][2];  // double-buffered B fragments (static-indexed: kt unrolled)

  auto stageH = [&](int slot, int kt, int h) {
    const f16* g = Abase + kt * 64 + (size_t)(h * 128) * 512;
    f16* l = LA[slot] + h * 8192 + tid * 8;
    gload_lds16(g, l);
    gload_lds16(g + (size_t)64 * 512, l + 4096);
  };

  // prologue: A KT0 both halves + KT1 h0; B KT0 -> buf0
  stageH(0, 0, 0); stageH(0, 0, 1); stageH(1, 1, 0);
#pragma unroll
  for (int nf = 0; nf < 4; ++nf)
#pragma unroll
    for (int ks = 0; ks < 2; ++ks)
      b_f[0][nf][ks] = *(const half8*)(bgp + (size_t)(nf * 16) * 512 + ks * 32);
  asm volatile("s_waitcnt vmcnt(10)" ::: "memory");  // 14 out - 4 (A KT0) = 10
  __builtin_amdgcn_s_barrier();

#pragma unroll
  for (int kt = 0; kt < 8; ++kt) {
    const f16* As = LA[kt & 1];
    const int cb = kt & 1;
    const int nb = (kt + 1) & 1;

    // ---- pA: ds_read a mh0; stage Ah1(kt+1) -> nsl; MFMA 32 (mh0 x all nh)
#pragma unroll
    for (int mf2 = 0; mf2 < 4; ++mf2) {
      a_f[mf2][0] = *(const half8*)(As + (arow + mf2 * 16) * 64 + cks0);
      a_f[mf2][1] = *(const half8*)(As + (arow + mf2 * 16) * 64 + cks1);
    }
    if (kt + 1 < 8) stageH(nb, kt + 1, 1);
    __builtin_amdgcn_s_setprio(1);
#pragma unroll
    for (int mf2 = 0; mf2 < 4; ++mf2)
#pragma unroll
      for (int nf = 0; nf < 4; ++nf)
#pragma unroll
        for (int ks = 0; ks < 2; ++ks)
          acc[mf2][nf] = __builtin_amdgcn_mfma_f32_16x16x32_f16(
              a_f[mf2][ks], b_f[cb][nf][ks], acc[mf2][nf], 0, 0, 0);
    __builtin_amdgcn_s_setprio(0);

    // ---- pB: ds_read a mh1; BG(kt+1)->nb; MFMA 32; barrier;
    //          stage Ah0(kt+2)->cur; vmcnt; barrier
#pragma unroll
    for (int mf2 = 0; mf2 < 4; ++mf2) {
      a_f[mf2][0] = *(const half8*)(As + (arow + 64 + mf2 * 16) * 64 + cks0);
      a_f[mf2][1] = *(const half8*)(As + (arow + 64 + mf2 * 16) * 64 + cks1);
    }
    if (kt + 1 < 8) {
#pragma unroll
      for (int nf = 0; nf < 4; ++nf)
#pragma unroll
        for (int ks = 0; ks < 2; ++ks)
          b_f[nb][nf][ks] = *(const half8*)(bgp + (size_t)(nf * 16) * 512 +
                                            (kt + 1) * 64 + ks * 32);
    }
    __builtin_amdgcn_s_setprio(1);
#pragma unroll
    for (int mf2 = 0; mf2 < 4; ++mf2)
#pragma unroll
      for (int nf = 0; nf < 4; ++nf)
#pragma unroll
        for (int ks = 0; ks < 2; ++ks)
          acc[4 + mf2][nf] = __builtin_amdgcn_mfma_f32_16x16x32_f16(
              a_f[mf2][ks], b_f[cb][nf][ks], acc[4 + mf2][nf], 0, 0, 0);
    __builtin_amdgcn_s_setprio(0);
    __builtin_amdgcn_s_barrier();  // all waves' reads of cur slot consumed
    if (kt + 2 < 8) stageH(kt & 1, kt + 2, 0);
    if (kt < 6) {
      asm volatile("s_waitcnt vmcnt(10)" ::: "memory");  // S(kt+1) landed
    } else if (kt == 6) {
      asm volatile("s_waitcnt vmcnt(8)" ::: "memory");   // no Ah0(8): 12-4=8
    }
    if (kt < 7) __builtin_amdgcn_s_barrier();
  }

  // ---- epilogue: per-wave 16x64 transpose (scratch aliases LA[0]) ->
  //      2x16B/lane plain stores; Q cols get +bias and *QSCALE.
  f16* escp = &LA[0][0];  // 8 waves x 16 x 72 f16 = 18KB (LA[0] is 32KB)
  float bias[4], scl[4];
#pragma unroll
  for (int nf = 0; nf < 4; ++nf) {
    const int n = n0 + wn * 64 + nf * 16 + l15;
    const bool isq = (n < 512);
    bias[nf] = isq ? qbias[n] : 0.0f;
    scl[nf]  = isq ? QSCALE : 1.0f;
  }
  const int rrow = lane >> 2;
  const int rcg  = lane & 3;
#pragma unroll
  for (int mf = 0; mf < 8; ++mf) {
#pragma unroll
    for (int nf = 0; nf < 4; ++nf)
#pragma unroll
      for (int j = 0; j < 4; ++j)
        escp[(wid * 16 + l4 * 4 + j) * 72 + nf * 16 + l15] =
            (f16)((acc[mf][nf][j] + bias[nf]) * scl[nf]);
    asm volatile("s_waitcnt lgkmcnt(0)" ::: "memory");
    half8 v0 = *(const half8*)(&escp[(wid * 16 + rrow) * 72 + rcg * 16]);
    half8 v1 = *(const half8*)(&escp[(wid * 16 + rrow) * 72 + rcg * 16 + 8]);
    asm volatile("" ::: "memory");
    f16* dst = Cqkv + (size_t)(m0 + wm * 128 + mf * 16 + rrow) * 2560 + n0 + wn * 64 + rcg * 16;
    *(half8*)dst = v0;
    *(half8*)(dst + 8) = v1;
  }
}

// ---------------------------------------------------------------------------
// Output GEMM (Wo): 128x128 tile 2-phase.
// fp32 out in (B,D,T,HW) layout, nontemporal stores.
__global__ __launch_bounds__(256) void gemmO_kernel(
    const f16* __restrict__ A, const f16* __restrict__ B,
    float* __restrict__ Out) {
  __shared__ f16 As[2][128 * 32];
  __shared__ f16 Bs[2][128 * 32];

  const int lin = blockIdx.x;
  const int cpx = (int)gridDim.x >> 3;
  const int o = (lin & 7) * cpx + (lin >> 3);
  const int nt = o >> 2;
  const int mt = o & 3;
  const int m0 = mt * 128;
  const int n0 = nt * 128;
  const int tid = threadIdx.x;
  const int lane = tid & 63;
  const int wid = tid >> 6;
  const int wm = wid >> 1, wn = wid & 1;
  const int l15 = lane & 15, l4 = lane >> 4;

  floatx4 acc[4][4] = {};

  const int srow = tid >> 2;
  const int skp = (((tid & 3) ^ ((tid >> 3) & 3))) * 8;
  const f16* ap = A + (size_t)(m0 + srow) * 512 + skp;
  const f16* bp = B + (size_t)(n0 + srow) * 512 + skp;

  auto stage = [&](int buf, int k0) {
    f16* asl = As[buf] + tid * 8;
    f16* bsl = Bs[buf] + tid * 8;
    gload_lds16(ap + k0, asl);
    gload_lds16(ap + (size_t)64 * 512 + k0, asl + 2048);
    gload_lds16(bp + k0, bsl);
    gload_lds16(bp + (size_t)64 * 512 + k0, bsl + 2048);
  };

  const int rc = (l4 ^ ((l15 >> 1) & 3)) * 8;

  stage(0, 0);
  __syncthreads();
  int cur = 0;
  for (int k0 = 0; k0 < 512; k0 += 32) {
    if (k0 + 32 < 512) stage(cur ^ 1, k0 + 32);
    half8 af[4], bf[4];
#pragma unroll
    for (int mf = 0; mf < 4; ++mf)
      af[mf] = *(const half8*)(As[cur] + (wm * 64 + mf * 16 + l15) * 32 + rc);
#pragma unroll
    for (int nf = 0; nf < 4; ++nf)
      bf[nf] = *(const half8*)(Bs[cur] + (wn * 64 + nf * 16 + l15) * 32 + rc);
#pragma unroll
    for (int mf = 0; mf < 4; ++mf)
#pragma unroll
      for (int nf = 0; nf < 4; ++nf)
        acc[mf][nf] = __builtin_amdgcn_mfma_f32_16x16x32_f16(af[mf], bf[nf], acc[mf][nf], 0, 0, 0);
    __syncthreads();
    cur ^= 1;
  }

  const int mbase = m0 + wm * 64;
  const int nbase = n0 + wn * 64;
#pragma unroll
  for (int nf = 0; nf < 4; ++nf) {
    const int m2 = nbase + nf * 16 + l15;
    const int bb = m2 / 24576;
    const int rem = m2 - bb * 24576;
    const int t = rem >> 8;
    const int hw = rem & 255;
    float* op = Out + ((size_t)bb * 512 * 96 + t) * 256 + hw;
#pragma unroll
    for (int mf = 0; mf < 4; ++mf) {
#pragma unroll
      for (int j = 0; j < 4; ++j) {
        const int d = mbase + mf * 16 + l4 * 4 + j;
        __builtin_nontemporal_store(acc[mf][nf][j], op + (size_t)d * 24576);
      }
    }
  }
}

// ---------------------------------------------------------------------------
// Attention (r8/r10 structure): one 3-wave block per (nn, head); wave w
// handles m-blocks 2w, 2w+1. Softmax in base 2 (Q pre-scaled by 0.125*log2e).
// QKV rows m=(nn*96+t), cols: [0,512)=Q(biased,scaled) [512,1024)=K
// [1024,1536)=KL [1536,2048)=VL [2048,2560)=V (all row-major).
// V/VL transposed ONCE into LDS per block; all PV operands are 16B LDS reads.
// O stored via per-wave LDS transpose -> 2x16B/lane contiguous stores.
__global__ __launch_bounds__(192) void attn_kernel(
    const f16* __restrict__ QKV, f16* __restrict__ AO, int n0chunk) {
  const int nn = blockIdx.x >> 3;
  const int h = blockIdx.x & 7;
  const int tid = threadIdx.x;
  const int wid = tid >> 6;
  const int lane = tid & 63;
  const int l15 = lane & 15, l4 = lane >> 4;
  const int nglob = n0chunk + nn;
  const int bb = nglob >> 8, hw = nglob & 255;

  __shared__ __align__(16) f16 VTl[64][112];   // V^T  [dh][t], tail cols unused
  __shared__ __align__(16) f16 VLTl[64][112];  // VL^T [dh][t], cols 96..112 zeroed
  __shared__ __align__(16) float locS[3][16][4];
  __shared__ __align__(16) f16 pS[3][16][104];
  __shared__ __align__(16) f16 pS2[3][16][40];
  __shared__ __align__(16) f16 oesc[3][16][72];

  const f16* base = QKV + (size_t)nn * 96 * 2560;

  // ---- stage V^T, VL^T (coalesced global half8 reads -> scalar LDS writes)
#pragma unroll
  for (int it = 0; it < 4; ++it) {
    const int r = (tid >> 3) + it * 24;
    const int c0 = (tid & 7) * 8;
    half8 v  = *(const half8*)(base + (size_t)r * 2560 + 2048 + h * 64 + c0);
    half8 vl = *(const half8*)(base + (size_t)r * 2560 + 1536 + h * 64 + c0);
#pragma unroll
    for (int j = 0; j < 8; ++j) {
      VTl[c0 + j][r]  = v[j];
      VLTl[c0 + j][r] = vl[j];
    }
  }
  if (tid < 128) {  // zero VL^T tail cols (out-of-window reads hit these)
    half8 z = {};
    *(half8*)(&VLTl[tid >> 1][96 + (tid & 1) * 8]) = z;
  }

  // ---- K fragments (persistent, global): col t' = l15 + nf*16, k-contiguous
  half8 kb[6][2];
#pragma unroll
  for (int nf = 0; nf < 6; ++nf)
#pragma unroll
    for (int kg = 0; kg < 2; ++kg)
      kb[nf][kg] = *(const half8*)(base + (size_t)(nf * 16 + l15) * 2560 + 512 + h * 64 + kg * 32 + l4 * 8);

  __syncthreads();  // V^T/VL^T staged

  for (int mb = wid * 2; mb < wid * 2 + 2; ++mb) {
    const int t0 = mb * 16;
    const int tb = (t0 >= 2) ? (t0 - 2) : 0;  // even window base
    const int d0 = t0 - 1 - tb;               // -1 (t0==0) or +1

    // ---- Q and KL-window fragment loads (global)
    half8 aq[2], kl1[2], kl2[2];
    {
      int r1 = t0 - 1 + l15; if (r1 < 0) r1 = 0;
      int r2 = t0 + 1 + l15; if (r2 > 95) r2 = 95;
#pragma unroll
      for (int kg = 0; kg < 2; ++kg) {
        aq[kg]  = *(const half8*)(base + (size_t)(t0 + l15) * 2560 + h * 64 + kg * 32 + l4 * 8);
        kl1[kg] = *(const half8*)(base + (size_t)r1 * 2560 + 1024 + h * 64 + kg * 32 + l4 * 8);
        kl2[kg] = *(const half8*)(base + (size_t)r2 * 2560 + 1024 + h * 64 + kg * 32 + l4 * 8);
      }
    }

    // ---- S = Q K^T (16x96) and band windows SL1/SL2 (16x16 each)
    floatx4 s[6] = {};
    floatx4 sl1 = {}, sl2 = {};
#pragma unroll
    for (int nf = 0; nf < 6; ++nf)
#pragma unroll
      for (int kg = 0; kg < 2; ++kg)
        s[nf] = __builtin_amdgcn_mfma_f32_16x16x32_f16(aq[kg], kb[nf][kg], s[nf], 0, 0, 0);
#pragma unroll
    for (int kg = 0; kg < 2; ++kg) {
      sl1 = __builtin_amdgcn_mfma_f32_16x16x32_f16(aq[kg], kl1[kg], sl1, 0, 0, 0);
      sl2 = __builtin_amdgcn_mfma_f32_16x16x32_f16(aq[kg], kl2[kg], sl2, 0, 0, 0);
    }

    // ---- PV operand loads from LDS (16B contiguous)
    half8 vb[4][3], vlb[4];
#pragma unroll
    for (int nf = 0; nf < 4; ++nf) {
#pragma unroll
      for (int kg = 0; kg < 3; ++kg)
        vb[nf][kg] = *(const half8*)(&VTl[nf * 16 + l15][kg * 32 + l4 * 8]);
      vlb[nf] = load_h8u(&VLTl[nf * 16 + l15][tb + l4 * 8]);
    }

    // ---- zero pS2, extract band logits -> locS
    {
      half8 z = {};
      f16* pz = &pS2[wid][0][0];
      *(half8*)(pz + lane * 8) = z;
      if (lane < 16) *(half8*)(pz + 512 + lane * 8) = z;
    }
#pragma unroll
    for (int j = 0; j < 4; ++j) {
      const int r = l4 * 4 + j;
      const int s1i = l15 - r;
      if (s1i >= 0 && s1i < 3) locS[wid][r][s1i] = sl1[j];
      const int s2i = l15 + 2 - r;
      if (l15 >= 14 && s2i >= 0 && s2i < 3) locS[wid][r][s2i] = sl2[j];
    }
    __syncthreads();

    // ---- softmax per row, base-2 (logits pre-scaled by log2e via QSCALE)
#pragma unroll
    for (int j = 0; j < 4; ++j) {
      const int row = l4 * 4 + j;
      float sv[6];
#pragma unroll
      for (int nf = 0; nf < 6; ++nf) sv[nf] = s[nf][j];
      float mx = sv[0];
#pragma unroll
      for (int nf = 1; nf < 6; ++nf) mx = fmaxf(mx, sv[nf]);
      for (int off = 1; off < 16; off <<= 1) mx = fmaxf(mx, __shfl_xor(mx, off, 64));
      const float l0 = (t0 + row >= 1)  ? locS[wid][row][0] : -__builtin_inff();
      const float l1 = locS[wid][row][1];
      const float l2 = (t0 + row <= 94) ? locS[wid][row][2] : -__builtin_inff();
      mx = fmaxf(mx, fmaxf(l0, fmaxf(l1, l2)));
      float e[6], sum = 0.f;
#pragma unroll
      for (int nf = 0; nf < 6; ++nf) {
        e[nf] = exp2f(sv[nf] - mx);
        sum += e[nf];
      }
      for (int off = 1; off < 16; off <<= 1) sum += __shfl_xor(sum, off, 64);
      const float e0 = exp2f(l0 - mx), e1 = exp2f(l1 - mx), e2 = exp2f(l2 - mx);
      sum += e0 + e1 + e2;
      const float rd = 1.0f / sum;
#pragma unroll
      for (int nf = 0; nf < 6; ++nf) pS[wid][row][nf * 16 + l15] = (f16)(e[nf] * rd);
      if (l15 < 3) {
        const int w = row + l15 + d0;
        const float ev = (l15 == 0) ? e0 : ((l15 == 1) ? e1 : e2);
        if (w >= 0) pS2[wid][row][w] = (f16)(ev * rd);
      }
    }
    __syncthreads();

    // ---- O = P @ V  +  P2 @ VL-window
    floatx4 o[4] = {};
    half8 pfr[3];
#pragma unroll
    for (int kg = 0; kg < 3; ++kg)
      pfr[kg] = *(const half8*)(&pS[wid][l15][kg * 32 + l4 * 8]);
    half8 pf2 = *(const half8*)(&pS2[wid][l15][l4 * 8]);
#pragma unroll
    for (int nf = 0; nf < 4; ++nf) {
#pragma unroll
      for (int kg = 0; kg < 3; ++kg)
        o[nf] = __builtin_amdgcn_mfma_f32_16x16x32_f16(pfr[kg], vb[nf][kg], o[nf], 0, 0, 0);
      o[nf] = __builtin_amdgcn_mfma_f32_16x16x32_f16(pf2, vlb[nf], o[nf], 0, 0, 0);
    }

    // ---- store via per-wave transpose: 2x16B contiguous per lane
#pragma unroll
    for (int nf = 0; nf < 4; ++nf)
#pragma unroll
      for (int j = 0; j < 4; ++j)
        oesc[wid][l4 * 4 + j][nf * 16 + l15] = (f16)o[nf][j];
    asm volatile("s_waitcnt lgkmcnt(0)" ::: "memory");
    {
      const int rrow = lane >> 2;
      const int rcg  = lane & 3;
      half8 v0 = *(const half8*)(&oesc[wid][rrow][rcg * 16]);
      half8 v1 = *(const half8*)(&oesc[wid][rrow][rcg * 16 + 8]);
      asm volatile("" ::: "memory");
      f16* dst = AO + ((size_t)(bb * 96 + t0 + rrow) * 256 + hw) * 512 + h * 64 + rcg * 16;
      *(half8*)dst = v0;
      *(half8*)(dst + 8) = v1;
    }
  }
}

// ---------------------------------------------------------------------------
extern "C" void kernel_launch(void* const* d_in, const int* in_sizes, int n_in,
                              void* d_out, int out_size, void* d_ws, size_t ws_size,
                              hipStream_t stream) {
  (void)in_sizes; (void)n_in; (void)out_size;
  const float* x     = (const float*)d_in[0];
  const float* gamma = (const float*)d_in[1];
  const float* beta  = (const float*)d_in[2];
  const float* Wq    = (const float*)d_in[3];
  const float* Wk    = (const float*)d_in[4];
  const float* Wv    = (const float*)d_in[5];
  const float* Wkl   = (const float*)d_in[6];
  const float* Wvl   = (const float*)d_in[7];
  const float* Wo    = (const float*)d_in[8];
  const float* qb    = (const float*)d_in[9];
  float* out = (float*)d_out;

  char* ws = (char*)d_ws;
  size_t off = 0;
  auto alloc = [&](size_t bytes) -> void* {
    void* p = ws + off;
    off += (bytes + 255) & ~(size_t)255;
    return p;
  };
  f16* XN   = (f16*)alloc((size_t)MTOT * 512 * 2);
  f16* AO   = (f16*)alloc((size_t)MTOT * 512 * 2);
  f16* WQKV = (f16*)alloc((size_t)2560 * 512 * 2);
  f16* WOh  = (f16*)alloc((size_t)512 * 512 * 2);
  // chunking over n (512 total) to bound workspace; need cn*96 % 256 == 0
  int cn = 512;
  while (cn > 32 && off + (size_t)cn * 96 * 2560 * 2 + 256 > ws_size)
    cn >>= 1;
  f16* QKVc = (f16*)alloc((size_t)cn * 96 * 2560 * 2);

  wconv_kernel<<<5120, 256, 0, stream>>>(Wq, Wk, Wv, Wkl, Wvl, Wo, WQKV, WOh);
  ln_kernel<<<768, 256, 0, stream>>>(x, gamma, beta, XN);

  const int nch = 512 / cn;
  for (int c = 0; c < nch; ++c) {
    const int mtiles = (cn * 96) / 256;
    gemmA_kernel<<<mtiles * 10, 512, 0, stream>>>(XN + (size_t)c * cn * 96 * 512,
                                                  WQKV, QKVc, qb);
    attn_kernel<<<cn * 8, 192, 0, stream>>>(QKVc, AO, c * cn);
  }
  gemmO_kernel<<<1536, 256, 0, stream>>>(WOh, AO, out);
}

// Round 16
// 391.470 us; speedup vs baseline: 1.0774x; 1.0774x over previous
//
#include <hip/hip_runtime.h>
#include <hip/hip_fp16.h>
#include <cstdint>
#include <cstddef>

typedef _Float16 f16;
typedef _Float16 half8 __attribute__((ext_vector_type(8)));
typedef _Float16 half4v __attribute__((ext_vector_type(4)));
typedef float floatx4 __attribute__((ext_vector_type(4)));

#define MTOT 49152  // B*T*HW rows total (=2*96*256), also = N_TOT*T
#define QSCALE 0.180336880111120426f  // 0.125 * log2(e): folds softmax base-2

// ---------------------------------------------------------------------------
// async global->LDS, 16B per lane
__device__ __forceinline__ void gload_lds16(const f16* g, f16* l) {
  __builtin_amdgcn_global_load_lds((const __attribute__((address_space(1))) void*)g,
                                   (__attribute__((address_space(3))) void*)l, 16, 0, 0);
}

// alignment-tolerant 16B load (addr may be only 4B-aligned)
__device__ __forceinline__ half8 load_h8u(const f16* p) {
  half8 v;
  __builtin_memcpy(&v, p, 16);
  return v;
}

// ---------------------------------------------------------------------------
// Convert weights fp32 -> f16. WQKV rows: [0,512)=Wq [512,1024)=Wk
// [1024,1536)=Wkl [1536,2048)=Wvl [2048,2560)=Wv.  WO separate.
__global__ __launch_bounds__(256) void wconv_kernel(
    const float* __restrict__ Wq, const float* __restrict__ Wk,
    const float* __restrict__ Wv, const float* __restrict__ Wkl,
    const float* __restrict__ Wvl, const float* __restrict__ Wo,
    f16* __restrict__ WQKV, f16* __restrict__ WO) {
  int idx = blockIdx.x * 256 + threadIdx.x;
  if (idx < 2560 * 512) {
    int row = idx >> 9;
    int col = idx & 511;
    int seg = row >> 9;
    int r = row & 511;
    const float* src;
    switch (seg) {
      case 0: src = Wq; break;
      case 1: src = Wk; break;
      case 2: src = Wkl; break;
      case 3: src = Wvl; break;
      default: src = Wv; break;
    }
    WQKV[idx] = (f16)src[r * 512 + col];
  }
  if (idx < 512 * 512) WO[idx] = (f16)Wo[idx];
}

// ---------------------------------------------------------------------------
// LayerNorm over D. x layout (B=2, D=512, T=96, HW=256).
// Output XN f16 row-major [m][512], m = (b*256+hw)*96 + t.
// x values register-cached (static unroll) -> single HBM read pass.
__global__ __launch_bounds__(256) void ln_kernel(
    const float* __restrict__ x, const float* __restrict__ gamma,
    const float* __restrict__ beta, f16* __restrict__ XN) {
  const int hwg = blockIdx.x & 3;
  const int t   = (blockIdx.x >> 2) % 96;
  const int b   = blockIdx.x / (4 * 96);
  const int lhw = threadIdx.x & 63;
  const int dg  = threadIdx.x >> 6;
  const int hw  = hwg * 64 + lhw;
  const float* xp = x + (size_t)b * 512 * 24576 + (size_t)t * 256 + hw +
                    (size_t)dg * 128 * 24576;

  float v[128];
  float s = 0.f, s2 = 0.f;
#pragma unroll
  for (int j = 0; j < 128; ++j) {
    float u = xp[(size_t)j * 24576];
    v[j] = u;
    s += u;
    s2 += u * u;
  }
  __shared__ float S1[4][64], S2[4][64];
  S1[dg][lhw] = s;
  S2[dg][lhw] = s2;
  __syncthreads();
  s  = S1[0][lhw] + S1[1][lhw] + S1[2][lhw] + S1[3][lhw];
  s2 = S2[0][lhw] + S2[1][lhw] + S2[2][lhw] + S2[3][lhw];
  const float mean = s * (1.f / 512.f);
  float var = s2 * (1.f / 512.f) - mean * mean;
  var = fmaxf(var, 0.f);
  const float rstd = rsqrtf(var + 1e-6f);
  const int n = b * 256 + hw;
  f16* outp = XN + ((size_t)n * 96 + t) * 512 + dg * 128;
#pragma unroll
  for (int d0 = 0; d0 < 128; d0 += 8) {
    half8 buf;
#pragma unroll
    for (int j = 0; j < 8; ++j) {
      const int d = dg * 128 + d0 + j;
      buf[j] = (f16)((v[d0 + j] - mean) * rstd * gamma[d] + beta[d]);
    }
    *(half8*)(outp + d0) = buf;
  }
}

// ---------------------------------------------------------------------------
// GEMM A (projections): C[m][n] = sum_k A[m][k]*B[n][k], K=512, N=2560.
// 256x256 tile, BK=64, 512 threads = 8 waves (2m x 4n), wave tile 128x64.
// r7/r13 schedule (best measured: 172us): shallow staging — per kt
// q0:A-h1(kt+1), q1:B-h0(kt+1), q2:B-h1(kt+1), q3:A-h0(kt+2, cur slot);
// vmcnt(2) at q3. setprio (T5), XOR swizzle (T2). Epilogue: per-wave LDS
// transpose -> 2x16B/lane plain stores; Q cols get +bias and *QSCALE.
// NOTE (r14 post-mortem): B direct-from-L2 regressed (172->218us) — staged
// LDS via global_load_lds beats register loads from L2 even when LDS BW
// looks binding; the async DMA queue hides latency, the cache tier doesn't.
__global__ __launch_bounds__(512, 2) void gemmA_kernel(
    const f16* __restrict__ A, const f16* __restrict__ B,
    f16* __restrict__ Cqkv, const float* __restrict__ qbias) {
  __shared__ f16 LA[2][256 * 64];
  __shared__ f16 LB[2][256 * 64];
  __shared__ __align__(16) f16 esc[8][16][72];

  const int lin = blockIdx.x;
  const int cpx = (int)gridDim.x >> 3;
  const int swz = (lin & 7) * cpx + (lin >> 3);
  const int o = ((gridDim.x & 7) == 0) ? swz : lin;  // bijective only if %8==0
  const int mt = o / 10;
  const int nt = o % 10;
  const int m0 = mt * 256;
  const int n0 = nt * 256;

  const int tid = threadIdx.x;
  const int wid = tid >> 6;
  const int lane = tid & 63;
  const int wm = wid >> 2;  // 0..1
  const int wn = wid & 3;   // 0..3
  const int l15 = lane & 15, l4 = lane >> 4;

  // staging: thread -> (row = tid>>3 [+128h +64j], chunk = tid&7); source
  // chunk pre-XOR by row&7 so LDS stays linear (rule #21)
  const int srow = tid >> 3;
  const int scol = ((tid & 7) ^ (srow & 7)) * 8;
  const f16* Abase = A + (size_t)(m0 + srow) * 512 + scol;
  const f16* Bbase = B + (size_t)(n0 + srow) * 512 + scol;

  // per-lane ds_read chunk offsets (row&7 == l15&7 on read side)
  const int cks0 = ((l4) ^ (l15 & 7)) * 8;
  const int cks1 = ((4 + l4) ^ (l15 & 7)) * 8;
  const int arow = wm * 128 + l15;
  const int brow = wn * 64 + l15;

  floatx4 acc[8][4] = {};
  half8 a_f[4][2];
  half8 b_f[4][2];

  auto stageH = [&](int slot, int kt, int mat, int h) {
    const f16* g = (mat ? Bbase : Abase) + kt * 64 + (size_t)(h * 128) * 512;
    f16* l = (mat ? LB[slot] : LA[slot]) + h * 8192 + tid * 8;
    gload_lds16(g, l);
    gload_lds16(g + (size_t)64 * 512, l + 4096);
  };

  // prologue: KT0 fully + KT1 A-h0; then wait KT0 landed (vmcnt(2))
  stageH(0, 0, 0, 0); stageH(0, 0, 0, 1);
  stageH(0, 0, 1, 0); stageH(0, 0, 1, 1);
  stageH(1, 1, 0, 0);
  asm volatile("s_waitcnt vmcnt(2)" ::: "memory");
  __builtin_amdgcn_s_barrier();

#pragma unroll
  for (int kt = 0; kt < 8; ++kt) {
    const f16* As = LA[kt & 1];
    const f16* Bs = LB[kt & 1];
    const int nsl = (kt + 1) & 1;

    // ---- q0: (mh0, nh0); stage A-h1 of KT kt+1
#pragma unroll
    for (int mf2 = 0; mf2 < 4; ++mf2) {
      a_f[mf2][0] = *(const half8*)(As + (arow + mf2 * 16) * 64 + cks0);
      a_f[mf2][1] = *(const half8*)(As + (arow + mf2 * 16) * 64 + cks1);
    }
#pragma unroll
    for (int nf = 0; nf < 2; ++nf) {
      b_f[nf][0] = *(const half8*)(Bs + (brow + nf * 16) * 64 + cks0);
      b_f[nf][1] = *(const half8*)(Bs + (brow + nf * 16) * 64 + cks1);
    }
    if (kt + 1 < 8) stageH(nsl, kt + 1, 0, 1);
    __builtin_amdgcn_s_barrier();
    __builtin_amdgcn_s_setprio(1);
#pragma unroll
    for (int mf2 = 0; mf2 < 4; ++mf2)
#pragma unroll
      for (int nf2 = 0; nf2 < 2; ++nf2)
#pragma unroll
        for (int ks = 0; ks < 2; ++ks)
          acc[mf2][nf2] = __builtin_amdgcn_mfma_f32_16x16x32_f16(
              a_f[mf2][ks], b_f[nf2][ks], acc[mf2][nf2], 0, 0, 0);
    __builtin_amdgcn_s_setprio(0);
    __builtin_amdgcn_s_barrier();

    // ---- q1: (mh0, nh1); stage B-h0 of KT kt+1
#pragma unroll
    for (int nf = 2; nf < 4; ++nf) {
      b_f[nf][0] = *(const half8*)(Bs + (brow + nf * 16) * 64 + cks0);
      b_f[nf][1] = *(const half8*)(Bs + (brow + nf * 16) * 64 + cks1);
    }
    if (kt + 1 < 8) stageH(nsl, kt + 1, 1, 0);
    __builtin_amdgcn_s_barrier();
    __builtin_amdgcn_s_setprio(1);
#pragma unroll
    for (int mf2 = 0; mf2 < 4; ++mf2)
#pragma unroll
      for (int nf2 = 0; nf2 < 2; ++nf2)
#pragma unroll
        for (int ks = 0; ks < 2; ++ks)
          acc[mf2][2 + nf2] = __builtin_amdgcn_mfma_f32_16x16x32_f16(
              a_f[mf2][ks], b_f[2 + nf2][ks], acc[mf2][2 + nf2], 0, 0, 0);
    __builtin_amdgcn_s_setprio(0);
    __builtin_amdgcn_s_barrier();

    // ---- q2: (mh1, nh0) — reload A with mh1; stage B-h1 of KT kt+1
#pragma unroll
    for (int mf2 = 0; mf2 < 4; ++mf2) {
      a_f[mf2][0] = *(const half8*)(As + (arow + 64 + mf2 * 16) * 64 + cks0);
      a_f[mf2][1] = *(const half8*)(As + (arow + 64 + mf2 * 16) * 64 + cks1);
    }
    if (kt + 1 < 8) stageH(nsl, kt + 1, 1, 1);
    __builtin_amdgcn_s_barrier();
    __builtin_amdgcn_s_setprio(1);
#pragma unroll
    for (int mf2 = 0; mf2 < 4; ++mf2)
#pragma unroll
      for (int nf2 = 0; nf2 < 2; ++nf2)
#pragma unroll
        for (int ks = 0; ks < 2; ++ks)
          acc[4 + mf2][nf2] = __builtin_amdgcn_mfma_f32_16x16x32_f16(
              a_f[mf2][ks], b_f[nf2][ks], acc[4 + mf2][nf2], 0, 0, 0);
    __builtin_amdgcn_s_setprio(0);
    __builtin_amdgcn_s_barrier();

    // ---- q3: (mh1, nh1); stage A-h0 of KT kt+2 into CURRENT slot
    if (kt + 2 < 8) stageH(kt & 1, kt + 2, 0, 0);
    __builtin_amdgcn_s_barrier();
    __builtin_amdgcn_s_setprio(1);
#pragma unroll
    for (int mf2 = 0; mf2 < 4; ++mf2)
#pragma unroll
      for (int nf2 = 0; nf2 < 2; ++nf2)
#pragma unroll
        for (int ks = 0; ks < 2; ++ks)
          acc[4 + mf2][2 + nf2] = __builtin_amdgcn_mfma_f32_16x16x32_f16(
              a_f[mf2][ks], b_f[2 + nf2][ks], acc[4 + mf2][2 + nf2], 0, 0, 0);
    __builtin_amdgcn_s_setprio(0);
    if (kt < 6) {
      asm volatile("s_waitcnt vmcnt(2)" ::: "memory");  // KT kt+1 landed
    } else if (kt == 6) {
      asm volatile("s_waitcnt vmcnt(0)" ::: "memory");  // drain for KT7
    }
    __builtin_amdgcn_s_barrier();
  }

  // ---- epilogue: per-wave 16x64 transpose -> 2x16B/lane plain stores
  float bias[4], scl[4];
#pragma unroll
  for (int nf = 0; nf < 4; ++nf) {
    const int n = n0 + wn * 64 + nf * 16 + l15;
    const bool isq = (n < 512);
    bias[nf] = isq ? qbias[n] : 0.0f;
    scl[nf]  = isq ? QSCALE : 1.0f;
  }
  const int rrow = lane >> 2;
  const int rcg  = lane & 3;
#pragma unroll
  for (int mf = 0; mf < 8; ++mf) {
#pragma unroll
    for (int nf = 0; nf < 4; ++nf)
#pragma unroll
      for (int j = 0; j < 4; ++j)
        esc[wid][l4 * 4 + j][nf * 16 + l15] = (f16)((acc[mf][nf][j] + bias[nf]) * scl[nf]);
    asm volatile("s_waitcnt lgkmcnt(0)" ::: "memory");
    half8 v0 = *(const half8*)(&esc[wid][rrow][rcg * 16]);
    half8 v1 = *(const half8*)(&esc[wid][rrow][rcg * 16 + 8]);
    asm volatile("" ::: "memory");
    f16* dst = Cqkv + (size_t)(m0 + wm * 128 + mf * 16 + rrow) * 2560 + n0 + wn * 64 + rcg * 16;
    *(half8*)dst = v0;
    *(half8*)(dst + 8) = v1;
  }
}

// ---------------------------------------------------------------------------
// Output GEMM (Wo): 128x128 tile 2-phase.
// fp32 out in (B,D,T,HW) layout, nontemporal stores.
__global__ __launch_bounds__(256) void gemmO_kernel(
    const f16* __restrict__ A, const f16* __restrict__ B,
    float* __restrict__ Out) {
  __shared__ f16 As[2][128 * 32];
  __shared__ f16 Bs[2][128 * 32];

  const int lin = blockIdx.x;
  const int cpx = (int)gridDim.x >> 3;
  const int o = (lin & 7) * cpx + (lin >> 3);
  const int nt = o >> 2;
  const int mt = o & 3;
  const int m0 = mt * 128;
  const int n0 = nt * 128;
  const int tid = threadIdx.x;
  const int lane = tid & 63;
  const int wid = tid >> 6;
  const int wm = wid >> 1, wn = wid & 1;
  const int l15 = lane & 15, l4 = lane >> 4;

  floatx4 acc[4][4] = {};

  const int srow = tid >> 2;
  const int skp = (((tid & 3) ^ ((tid >> 3) & 3))) * 8;
  const f16* ap = A + (size_t)(m0 + srow) * 512 + skp;
  const f16* bp = B + (size_t)(n0 + srow) * 512 + skp;

  auto stage = [&](int buf, int k0) {
    f16* asl = As[buf] + tid * 8;
    f16* bsl = Bs[buf] + tid * 8;
    gload_lds16(ap + k0, asl);
    gload_lds16(ap + (size_t)64 * 512 + k0, asl + 2048);
    gload_lds16(bp + k0, bsl);
    gload_lds16(bp + (size_t)64 * 512 + k0, bsl + 2048);
  };

  const int rc = (l4 ^ ((l15 >> 1) & 3)) * 8;

  stage(0, 0);
  __syncthreads();
  int cur = 0;
  for (int k0 = 0; k0 < 512; k0 += 32) {
    if (k0 + 32 < 512) stage(cur ^ 1, k0 + 32);
    half8 af[4], bf[4];
#pragma unroll
    for (int mf = 0; mf < 4; ++mf)
      af[mf] = *(const half8*)(As[cur] + (wm * 64 + mf * 16 + l15) * 32 + rc);
#pragma unroll
    for (int nf = 0; nf < 4; ++nf)
      bf[nf] = *(const half8*)(Bs[cur] + (wn * 64 + nf * 16 + l15) * 32 + rc);
#pragma unroll
    for (int mf = 0; mf < 4; ++mf)
#pragma unroll
      for (int nf = 0; nf < 4; ++nf)
        acc[mf][nf] = __builtin_amdgcn_mfma_f32_16x16x32_f16(af[mf], bf[nf], acc[mf][nf], 0, 0, 0);
    __syncthreads();
    cur ^= 1;
  }

  const int mbase = m0 + wm * 64;
  const int nbase = n0 + wn * 64;
#pragma unroll
  for (int nf = 0; nf < 4; ++nf) {
    const int m2 = nbase + nf * 16 + l15;
    const int bb = m2 / 24576;
    const int rem = m2 - bb * 24576;
    const int t = rem >> 8;
    const int hw = rem & 255;
    float* op = Out + ((size_t)bb * 512 * 96 + t) * 256 + hw;
#pragma unroll
    for (int mf = 0; mf < 4; ++mf) {
#pragma unroll
      for (int j = 0; j < 4; ++j) {
        const int d = mbase + mf * 16 + l4 * 4 + j;
        __builtin_nontemporal_store(acc[mf][nf][j], op + (size_t)d * 24576);
      }
    }
  }
}

// ---------------------------------------------------------------------------
// Attention (r8/r10 structure): one 3-wave block per (nn, head); wave w
// handles m-blocks 2w, 2w+1. Softmax in base 2 (Q pre-scaled by 0.125*log2e).
// QKV rows m=(nn*96+t), cols: [0,512)=Q(biased,scaled) [512,1024)=K
// [1024,1536)=KL [1536,2048)=VL [2048,2560)=V (all row-major).
// V/VL transposed ONCE into LDS per block; all PV operands are 16B LDS reads.
// O stored via per-wave LDS transpose -> 2x16B/lane contiguous stores.
__global__ __launch_bounds__(192) void attn_kernel(
    const f16* __restrict__ QKV, f16* __restrict__ AO, int n0chunk) {
  const int nn = blockIdx.x >> 3;
  const int h = blockIdx.x & 7;
  const int tid = threadIdx.x;
  const int wid = tid >> 6;
  const int lane = tid & 63;
  const int l15 = lane & 15, l4 = lane >> 4;
  const int nglob = n0chunk + nn;
  const int bb = nglob >> 8, hw = nglob & 255;

  __shared__ __align__(16) f16 VTl[64][112];   // V^T  [dh][t], tail cols unused
  __shared__ __align__(16) f16 VLTl[64][112];  // VL^T [dh][t], cols 96..112 zeroed
  __shared__ __align__(16) float locS[3][16][4];
  __shared__ __align__(16) f16 pS[3][16][104];
  __shared__ __align__(16) f16 pS2[3][16][40];
  __shared__ __align__(16) f16 oesc[3][16][72];

  const f16* base = QKV + (size_t)nn * 96 * 2560;

  // ---- stage V^T, VL^T (coalesced global half8 reads -> scalar LDS writes)
#pragma unroll
  for (int it = 0; it < 4; ++it) {
    const int r = (tid >> 3) + it * 24;
    const int c0 = (tid & 7) * 8;
    half8 v  = *(const half8*)(base + (size_t)r * 2560 + 2048 + h * 64 + c0);
    half8 vl = *(const half8*)(base + (size_t)r * 2560 + 1536 + h * 64 + c0);
#pragma unroll
    for (int j = 0; j < 8; ++j) {
      VTl[c0 + j][r]  = v[j];
      VLTl[c0 + j][r] = vl[j];
    }
  }
  if (tid < 128) {  // zero VL^T tail cols (out-of-window reads hit these)
    half8 z = {};
    *(half8*)(&VLTl[tid >> 1][96 + (tid & 1) * 8]) = z;
  }

  // ---- K fragments (persistent, global): col t' = l15 + nf*16, k-contiguous
  half8 kb[6][2];
#pragma unroll
  for (int nf = 0; nf < 6; ++nf)
#pragma unroll
    for (int kg = 0; kg < 2; ++kg)
      kb[nf][kg] = *(const half8*)(base + (size_t)(nf * 16 + l15) * 2560 + 512 + h * 64 + kg * 32 + l4 * 8);

  __syncthreads();  // V^T/VL^T staged

  for (int mb = wid * 2; mb < wid * 2 + 2; ++mb) {
    const int t0 = mb * 16;
    const int tb = (t0 >= 2) ? (t0 - 2) : 0;  // even window base
    const int d0 = t0 - 1 - tb;               // -1 (t0==0) or +1

    // ---- Q and KL-window fragment loads (global)
    half8 aq[2], kl1[2], kl2[2];
    {
      int r1 = t0 - 1 + l15; if (r1 < 0) r1 = 0;
      int r2 = t0 + 1 + l15; if (r2 > 95) r2 = 95;
#pragma unroll
      for (int kg = 0; kg < 2; ++kg) {
        aq[kg]  = *(const half8*)(base + (size_t)(t0 + l15) * 2560 + h * 64 + kg * 32 + l4 * 8);
        kl1[kg] = *(const half8*)(base + (size_t)r1 * 2560 + 1024 + h * 64 + kg * 32 + l4 * 8);
        kl2[kg] = *(const half8*)(base + (size_t)r2 * 2560 + 1024 + h * 64 + kg * 32 + l4 * 8);
      }
    }

    // ---- S = Q K^T (16x96) and band windows SL1/SL2 (16x16 each)
    floatx4 s[6] = {};
    floatx4 sl1 = {}, sl2 = {};
#pragma unroll
    for (int nf = 0; nf < 6; ++nf)
#pragma unroll
      for (int kg = 0; kg < 2; ++kg)
        s[nf] = __builtin_amdgcn_mfma_f32_16x16x32_f16(aq[kg], kb[nf][kg], s[nf], 0, 0, 0);
#pragma unroll
    for (int kg = 0; kg < 2; ++kg) {
      sl1 = __builtin_amdgcn_mfma_f32_16x16x32_f16(aq[kg], kl1[kg], sl1, 0, 0, 0);
      sl2 = __builtin_amdgcn_mfma_f32_16x16x32_f16(aq[kg], kl2[kg], sl2, 0, 0, 0);
    }

    // ---- PV operand loads from LDS (16B contiguous)
    half8 vb[4][3], vlb[4];
#pragma unroll
    for (int nf = 0; nf < 4; ++nf) {
#pragma unroll
      for (int kg = 0; kg < 3; ++kg)
        vb[nf][kg] = *(const half8*)(&VTl[nf * 16 + l15][kg * 32 + l4 * 8]);
      vlb[nf] = load_h8u(&VLTl[nf * 16 + l15][tb + l4 * 8]);
    }

    // ---- zero pS2, extract band logits -> locS
    {
      half8 z = {};
      f16* pz = &pS2[wid][0][0];
      *(half8*)(pz + lane * 8) = z;
      if (lane < 16) *(half8*)(pz + 512 + lane * 8) = z;
    }
#pragma unroll
    for (int j = 0; j < 4; ++j) {
      const int r = l4 * 4 + j;
      const int s1i = l15 - r;
      if (s1i >= 0 && s1i < 3) locS[wid][r][s1i] = sl1[j];
      const int s2i = l15 + 2 - r;
      if (l15 >= 14 && s2i >= 0 && s2i < 3) locS[wid][r][s2i] = sl2[j];
    }
    __syncthreads();

    // ---- softmax per row, base-2 (logits pre-scaled by log2e via QSCALE)
#pragma unroll
    for (int j = 0; j < 4; ++j) {
      const int row = l4 * 4 + j;
      float sv[6];
#pragma unroll
      for (int nf = 0; nf < 6; ++nf) sv[nf] = s[nf][j];
      float mx = sv[0];
#pragma unroll
      for (int nf = 1; nf < 6; ++nf) mx = fmaxf(mx, sv[nf]);
      for (int off = 1; off < 16; off <<= 1) mx = fmaxf(mx, __shfl_xor(mx, off, 64));
      const float l0 = (t0 + row >= 1)  ? locS[wid][row][0] : -__builtin_inff();
      const float l1 = locS[wid][row][1];
      const float l2 = (t0 + row <= 94) ? locS[wid][row][2] : -__builtin_inff();
      mx = fmaxf(mx, fmaxf(l0, fmaxf(l1, l2)));
      float e[6], sum = 0.f;
#pragma unroll
      for (int nf = 0; nf < 6; ++nf) {
        e[nf] = exp2f(sv[nf] - mx);
        sum += e[nf];
      }
      for (int off = 1; off < 16; off <<= 1) sum += __shfl_xor(sum, off, 64);
      const float e0 = exp2f(l0 - mx), e1 = exp2f(l1 - mx), e2 = exp2f(l2 - mx);
      sum += e0 + e1 + e2;
      const float rd = 1.0f / sum;
#pragma unroll
      for (int nf = 0; nf < 6; ++nf) pS[wid][row][nf * 16 + l15] = (f16)(e[nf] * rd);
      if (l15 < 3) {
        const int w = row + l15 + d0;
        const float ev = (l15 == 0) ? e0 : ((l15 == 1) ? e1 : e2);
        if (w >= 0) pS2[wid][row][w] = (f16)(ev * rd);
      }
    }
    __syncthreads();

    // ---- O = P @ V  +  P2 @ VL-window
    floatx4 o[4] = {};
    half8 pfr[3];
#pragma unroll
    for (int kg = 0; kg < 3; ++kg)
      pfr[kg] = *(const half8*)(&pS[wid][l15][kg * 32 + l4 * 8]);
    half8 pf2 = *(const half8*)(&pS2[wid][l15][l4 * 8]);
#pragma unroll
    for (int nf = 0; nf < 4; ++nf) {
#pragma unroll
      for (int kg = 0; kg < 3; ++kg)
        o[nf] = __builtin_amdgcn_mfma_f32_16x16x32_f16(pfr[kg], vb[nf][kg], o[nf], 0, 0, 0);
      o[nf] = __builtin_amdgcn_mfma_f32_16x16x32_f16(pf2, vlb[nf], o[nf], 0, 0, 0);
    }

    // ---- store via per-wave transpose: 2x16B contiguous per lane
#pragma unroll
    for (int nf = 0; nf < 4; ++nf)
#pragma unroll
      for (int j = 0; j < 4; ++j)
        oesc[wid][l4 * 4 + j][nf * 16 + l15] = (f16)o[nf][j];
    asm volatile("s_waitcnt lgkmcnt(0)" ::: "memory");
    {
      const int rrow = lane >> 2;
      const int rcg  = lane & 3;
      half8 v0 = *(const half8*)(&oesc[wid][rrow][rcg * 16]);
      half8 v1 = *(const half8*)(&oesc[wid][rrow][rcg * 16 + 8]);
      asm volatile("" ::: "memory");
      f16* dst = AO + ((size_t)(bb * 96 + t0 + rrow) * 256 + hw) * 512 + h * 64 + rcg * 16;
      *(half8*)dst = v0;
      *(half8*)(dst + 8) = v1;
    }
  }
}

// ---------------------------------------------------------------------------
extern "C" void kernel_launch(void* const* d_in, const int* in_sizes, int n_in,
                              void* d_out, int out_size, void* d_ws, size_t ws_size,
                              hipStream_t stream) {
  (void)in_sizes; (void)n_in; (void)out_size;
  const float* x     = (const float*)d_in[0];
  const float* gamma = (const float*)d_in[1];
  const float* beta  = (const float*)d_in[2];
  const float* Wq    = (const float*)d_in[3];
  const float* Wk    = (const float*)d_in[4];
  const float* Wv    = (const float*)d_in[5];
  const float* Wkl   = (const float*)d_in[6];
  const float* Wvl   = (const float*)d_in[7];
  const float* Wo    = (const float*)d_in[8];
  const float* qb    = (const float*)d_in[9];
  float* out = (float*)d_out;

  char* ws = (char*)d_ws;
  size_t off = 0;
  auto alloc = [&](size_t bytes) -> void* {
    void* p = ws + off;
    off += (bytes + 255) & ~(size_t)255;
    return p;
  };
  f16* XN   = (f16*)alloc((size_t)MTOT * 512 * 2);
  f16* AO   = (f16*)alloc((size_t)MTOT * 512 * 2);
  f16* WQKV = (f16*)alloc((size_t)2560 * 512 * 2);
  f16* WOh  = (f16*)alloc((size_t)512 * 512 * 2);
  // chunking over n (512 total) to bound workspace; need cn*96 % 256 == 0
  int cn = 512;
  while (cn > 32 && off + (size_t)cn * 96 * 2560 * 2 + 256 > ws_size)
    cn >>= 1;
  f16* QKVc = (f16*)alloc((size_t)cn * 96 * 2560 * 2);

  wconv_kernel<<<5120, 256, 0, stream>>>(Wq, Wk, Wv, Wkl, Wvl, Wo, WQKV, WOh);
  ln_kernel<<<768, 256, 0, stream>>>(x, gamma, beta, XN);

  const int nch = 512 / cn;
  for (int c = 0; c < nch; ++c) {
    const int mtiles = (cn * 96) / 256;
    gemmA_kernel<<<mtiles * 10, 512, 0, stream>>>(XN + (size_t)c * cn * 96 * 512,
                                                  WQKV, QKVc, qb);
    attn_kernel<<<cn * 8, 192, 0, stream>>>(QKVc, AO, c * cn);
  }
  gemmO_kernel<<<1536, 256, 0, stream>>>(WOh, AO, out);
}

// Round 17
// 384.822 us; speedup vs baseline: 1.0960x; 1.0173x over previous
//
#include <hip/hip_runtime.h>
#include <hip/hip_fp16.h>
#include <cstdint>
#include <cstddef>

typedef _Float16 f16;
typedef _Float16 half8 __attribute__((ext_vector_type(8)));
typedef _Float16 half4v __attribute__((ext_vector_type(4)));
typedef float floatx4 __attribute__((ext_vector_type(4)));

#define MTOT 49152  // B*T*HW rows total (=2*96*256), also = N_TOT*T
#define QSCALE 0.180336880111120426f  // 0.125 * log2(e): folds softmax base-2

// ---------------------------------------------------------------------------
// async global->LDS, 16B per lane
__device__ __forceinline__ void gload_lds16(const f16* g, f16* l) {
  __builtin_amdgcn_global_load_lds((const __attribute__((address_space(1))) void*)g,
                                   (__attribute__((address_space(3))) void*)l, 16, 0, 0);
}

// alignment-tolerant 16B load (addr may be only 4B-aligned)
__device__ __forceinline__ half8 load_h8u(const f16* p) {
  half8 v;
  __builtin_memcpy(&v, p, 16);
  return v;
}

// ---------------------------------------------------------------------------
// Convert weights fp32 -> f16. WQKV rows: [0,512)=Wq [512,1024)=Wk
// [1024,1536)=Wkl [1536,2048)=Wvl [2048,2560)=Wv.  WO separate.
__global__ __launch_bounds__(256) void wconv_kernel(
    const float* __restrict__ Wq, const float* __restrict__ Wk,
    const float* __restrict__ Wv, const float* __restrict__ Wkl,
    const float* __restrict__ Wvl, const float* __restrict__ Wo,
    f16* __restrict__ WQKV, f16* __restrict__ WO) {
  int idx = blockIdx.x * 256 + threadIdx.x;
  if (idx < 2560 * 512) {
    int row = idx >> 9;
    int col = idx & 511;
    int seg = row >> 9;
    int r = row & 511;
    const float* src;
    switch (seg) {
      case 0: src = Wq; break;
      case 1: src = Wk; break;
      case 2: src = Wkl; break;
      case 3: src = Wvl; break;
      default: src = Wv; break;
    }
    WQKV[idx] = (f16)src[r * 512 + col];
  }
  if (idx < 512 * 512) WO[idx] = (f16)Wo[idx];
}

// ---------------------------------------------------------------------------
// LayerNorm over D. x layout (B=2, D=512, T=96, HW=256).
// Output XN f16 row-major [m][512], m = (b*256+hw)*96 + t.
// x register-cached (single HBM read pass). Output goes through a 64KB LDS
// transpose tile (chunk-XOR swizzled both sides) so each 4-lane group stores
// 64B contiguous XN segments — fixes the ~4x write amplification of the
// direct 16B-at-98KB-stride stores.
__global__ __launch_bounds__(256) void ln_kernel(
    const float* __restrict__ x, const float* __restrict__ gamma,
    const float* __restrict__ beta, f16* __restrict__ XN) {
  const int hwg = blockIdx.x & 3;
  const int t   = (blockIdx.x >> 2) % 96;
  const int b   = blockIdx.x / (4 * 96);
  const int lhw = threadIdx.x & 63;
  const int dg  = threadIdx.x >> 6;
  const float* xp = x + (size_t)b * 512 * 24576 + (size_t)t * 256 +
                    (hwg * 64 + lhw) + (size_t)dg * 128 * 24576;

  float v[128];
  float s = 0.f, s2 = 0.f;
#pragma unroll
  for (int j = 0; j < 128; ++j) {
    float u = xp[(size_t)j * 24576];
    v[j] = u;
    s += u;
    s2 += u * u;
  }
  __shared__ float S1[4][64], S2[4][64];
  __shared__ __align__(16) f16 XT[64][512];  // transpose tile, 64KB
  S1[dg][lhw] = s;
  S2[dg][lhw] = s2;
  __syncthreads();
  s  = S1[0][lhw] + S1[1][lhw] + S1[2][lhw] + S1[3][lhw];
  s2 = S2[0][lhw] + S2[1][lhw] + S2[2][lhw] + S2[3][lhw];
  const float mean = s * (1.f / 512.f);
  float var = s2 * (1.f / 512.f) - mean * mean;
  var = fmaxf(var, 0.f);
  const float rstd = rsqrtf(var + 1e-6f);

  // write normalized values into XT row lhw, chunks dg*16..dg*16+15, XOR-swz
#pragma unroll
  for (int ic = 0; ic < 16; ++ic) {
    const int c = dg * 16 + ic;
    const int slot = c ^ (lhw & 7);
    half8 buf;
#pragma unroll
    for (int j = 0; j < 8; ++j) {
      const int d = c * 8 + j;
      buf[j] = (f16)((v[ic * 8 + j] - mean) * rstd * gamma[d] + beta[d]);
    }
    *(half8*)(&XT[lhw][slot * 8]) = buf;
  }
  __syncthreads();

  // read back: thread (rr=tid>>2, seg=tid&3) emits row rr, chunks i*4+seg
  const int rr = threadIdx.x >> 2;
  const int seg = threadIdx.x & 3;
  const int n = b * 256 + hwg * 64 + rr;
  f16* outp = XN + ((size_t)n * 96 + t) * 512;
#pragma unroll
  for (int i = 0; i < 16; ++i) {
    const int c = i * 4 + seg;
    const int slot = c ^ (rr & 7);
    half8 w = *(const half8*)(&XT[rr][slot * 8]);
    *(half8*)(outp + c * 8) = w;
  }
}

// ---------------------------------------------------------------------------
// GEMM A (projections): C[m][n] = sum_k A[m][k]*B[n][k], K=512, N=2560.
// 256x256 tile, BK=64, 512 threads = 8 waves (2m x 4n), wave tile 128x64.
// r7/r13 schedule (best measured: 172us): shallow staging — per kt
// q0:A-h1(kt+1), q1:B-h0(kt+1), q2:B-h1(kt+1), q3:A-h0(kt+2, cur slot);
// vmcnt(2) at q3. setprio (T5), XOR swizzle (T2). Epilogue: per-wave LDS
// transpose -> 2x16B/lane plain stores; Q cols get +bias and *QSCALE.
// NOTE (r14 post-mortem): B direct-from-L2 regressed (172->218us) — staged
// LDS via global_load_lds beats register loads from L2 even when LDS BW
// looks binding; the async DMA queue hides latency, the cache tier doesn't.
__global__ __launch_bounds__(512, 2) void gemmA_kernel(
    const f16* __restrict__ A, const f16* __restrict__ B,
    f16* __restrict__ Cqkv, const float* __restrict__ qbias) {
  __shared__ f16 LA[2][256 * 64];
  __shared__ f16 LB[2][256 * 64];
  __shared__ __align__(16) f16 esc[8][16][72];

  const int lin = blockIdx.x;
  const int cpx = (int)gridDim.x >> 3;
  const int swz = (lin & 7) * cpx + (lin >> 3);
  const int o = ((gridDim.x & 7) == 0) ? swz : lin;  // bijective only if %8==0
  const int mt = o / 10;
  const int nt = o % 10;
  const int m0 = mt * 256;
  const int n0 = nt * 256;

  const int tid = threadIdx.x;
  const int wid = tid >> 6;
  const int lane = tid & 63;
  const int wm = wid >> 2;  // 0..1
  const int wn = wid & 3;   // 0..3
  const int l15 = lane & 15, l4 = lane >> 4;

  // staging: thread -> (row = tid>>3 [+128h +64j], chunk = tid&7); source
  // chunk pre-XOR by row&7 so LDS stays linear (rule #21)
  const int srow = tid >> 3;
  const int scol = ((tid & 7) ^ (srow & 7)) * 8;
  const f16* Abase = A + (size_t)(m0 + srow) * 512 + scol;
  const f16* Bbase = B + (size_t)(n0 + srow) * 512 + scol;

  // per-lane ds_read chunk offsets (row&7 == l15&7 on read side)
  const int cks0 = ((l4) ^ (l15 & 7)) * 8;
  const int cks1 = ((4 + l4) ^ (l15 & 7)) * 8;
  const int arow = wm * 128 + l15;
  const int brow = wn * 64 + l15;

  floatx4 acc[8][4] = {};
  half8 a_f[4][2];
  half8 b_f[4][2];

  auto stageH = [&](int slot, int kt, int mat, int h) {
    const f16* g = (mat ? Bbase : Abase) + kt * 64 + (size_t)(h * 128) * 512;
    f16* l = (mat ? LB[slot] : LA[slot]) + h * 8192 + tid * 8;
    gload_lds16(g, l);
    gload_lds16(g + (size_t)64 * 512, l + 4096);
  };

  // prologue: KT0 fully + KT1 A-h0; then wait KT0 landed (vmcnt(2))
  stageH(0, 0, 0, 0); stageH(0, 0, 0, 1);
  stageH(0, 0, 1, 0); stageH(0, 0, 1, 1);
  stageH(1, 1, 0, 0);
  asm volatile("s_waitcnt vmcnt(2)" ::: "memory");
  __builtin_amdgcn_s_barrier();

#pragma unroll
  for (int kt = 0; kt < 8; ++kt) {
    const f16* As = LA[kt & 1];
    const f16* Bs = LB[kt & 1];
    const int nsl = (kt + 1) & 1;

    // ---- q0: (mh0, nh0); stage A-h1 of KT kt+1
#pragma unroll
    for (int mf2 = 0; mf2 < 4; ++mf2) {
      a_f[mf2][0] = *(const half8*)(As + (arow + mf2 * 16) * 64 + cks0);
      a_f[mf2][1] = *(const half8*)(As + (arow + mf2 * 16) * 64 + cks1);
    }
#pragma unroll
    for (int nf = 0; nf < 2; ++nf) {
      b_f[nf][0] = *(const half8*)(Bs + (brow + nf * 16) * 64 + cks0);
      b_f[nf][1] = *(const half8*)(Bs + (brow + nf * 16) * 64 + cks1);
    }
    if (kt + 1 < 8) stageH(nsl, kt + 1, 0, 1);
    __builtin_amdgcn_s_barrier();
    __builtin_amdgcn_s_setprio(1);
#pragma unroll
    for (int mf2 = 0; mf2 < 4; ++mf2)
#pragma unroll
      for (int nf2 = 0; nf2 < 2; ++nf2)
#pragma unroll
        for (int ks = 0; ks < 2; ++ks)
          acc[mf2][nf2] = __builtin_amdgcn_mfma_f32_16x16x32_f16(
              a_f[mf2][ks], b_f[nf2][ks], acc[mf2][nf2], 0, 0, 0);
    __builtin_amdgcn_s_setprio(0);
    __builtin_amdgcn_s_barrier();

    // ---- q1: (mh0, nh1); stage B-h0 of KT kt+1
#pragma unroll
    for (int nf = 2; nf < 4; ++nf) {
      b_f[nf][0] = *(const half8*)(Bs + (brow + nf * 16) * 64 + cks0);
      b_f[nf][1] = *(const half8*)(Bs + (brow + nf * 16) * 64 + cks1);
    }
    if (kt + 1 < 8) stageH(nsl, kt + 1, 1, 0);
    __builtin_amdgcn_s_barrier();
    __builtin_amdgcn_s_setprio(1);
#pragma unroll
    for (int mf2 = 0; mf2 < 4; ++mf2)
#pragma unroll
      for (int nf2 = 0; nf2 < 2; ++nf2)
#pragma unroll
        for (int ks = 0; ks < 2; ++ks)
          acc[mf2][2 + nf2] = __builtin_amdgcn_mfma_f32_16x16x32_f16(
              a_f[mf2][ks], b_f[2 + nf2][ks], acc[mf2][2 + nf2], 0, 0, 0);
    __builtin_amdgcn_s_setprio(0);
    __builtin_amdgcn_s_barrier();

    // ---- q2: (mh1, nh0) — reload A with mh1; stage B-h1 of KT kt+1
#pragma unroll
    for (int mf2 = 0; mf2 < 4; ++mf2) {
      a_f[mf2][0] = *(const half8*)(As + (arow + 64 + mf2 * 16) * 64 + cks0);
      a_f[mf2][1] = *(const half8*)(As + (arow + 64 + mf2 * 16) * 64 + cks1);
    }
    if (kt + 1 < 8) stageH(nsl, kt + 1, 1, 1);
    __builtin_amdgcn_s_barrier();
    __builtin_amdgcn_s_setprio(1);
#pragma unroll
    for (int mf2 = 0; mf2 < 4; ++mf2)
#pragma unroll
      for (int nf2 = 0; nf2 < 2; ++nf2)
#pragma unroll
        for (int ks = 0; ks < 2; ++ks)
          acc[4 + mf2][nf2] = __builtin_amdgcn_mfma_f32_16x16x32_f16(
              a_f[mf2][ks], b_f[nf2][ks], acc[4 + mf2][nf2], 0, 0, 0);
    __builtin_amdgcn_s_setprio(0);
    __builtin_amdgcn_s_barrier();

    // ---- q3: (mh1, nh1); stage A-h0 of KT kt+2 into CURRENT slot
    if (kt + 2 < 8) stageH(kt & 1, kt + 2, 0, 0);
    __builtin_amdgcn_s_barrier();
    __builtin_amdgcn_s_setprio(1);
#pragma unroll
    for (int mf2 = 0; mf2 < 4; ++mf2)
#pragma unroll
      for (int nf2 = 0; nf2 < 2; ++nf2)
#pragma unroll
        for (int ks = 0; ks < 2; ++ks)
          acc[4 + mf2][2 + nf2] = __builtin_amdgcn_mfma_f32_16x16x32_f16(
              a_f[mf2][ks], b_f[2 + nf2][ks], acc[4 + mf2][2 + nf2], 0, 0, 0);
    __builtin_amdgcn_s_setprio(0);
    if (kt < 6) {
      asm volatile("s_waitcnt vmcnt(2)" ::: "memory");  // KT kt+1 landed
    } else if (kt == 6) {
      asm volatile("s_waitcnt vmcnt(0)" ::: "memory");  // drain for KT7
    }
    __builtin_amdgcn_s_barrier();
  }

  // ---- epilogue: per-wave 16x64 transpose -> 2x16B/lane plain stores
  float bias[4], scl[4];
#pragma unroll
  for (int nf = 0; nf < 4; ++nf) {
    const int n = n0 + wn * 64 + nf * 16 + l15;
    const bool isq = (n < 512);
    bias[nf] = isq ? qbias[n] : 0.0f;
    scl[nf]  = isq ? QSCALE : 1.0f;
  }
  const int rrow = lane >> 2;
  const int rcg  = lane & 3;
#pragma unroll
  for (int mf = 0; mf < 8; ++mf) {
#pragma unroll
    for (int nf = 0; nf < 4; ++nf)
#pragma unroll
      for (int j = 0; j < 4; ++j)
        esc[wid][l4 * 4 + j][nf * 16 + l15] = (f16)((acc[mf][nf][j] + bias[nf]) * scl[nf]);
    asm volatile("s_waitcnt lgkmcnt(0)" ::: "memory");
    half8 v0 = *(const half8*)(&esc[wid][rrow][rcg * 16]);
    half8 v1 = *(const half8*)(&esc[wid][rrow][rcg * 16 + 8]);
    asm volatile("" ::: "memory");
    f16* dst = Cqkv + (size_t)(m0 + wm * 128 + mf * 16 + rrow) * 2560 + n0 + wn * 64 + rcg * 16;
    *(half8*)dst = v0;
    *(half8*)(dst + 8) = v1;
  }
}

// ---------------------------------------------------------------------------
// Output GEMM (Wo): 128x128 tile 2-phase.
// fp32 out in (B,D,T,HW) layout, nontemporal stores.
__global__ __launch_bounds__(256) void gemmO_kernel(
    const f16* __restrict__ A, const f16* __restrict__ B,
    float* __restrict__ Out) {
  __shared__ f16 As[2][128 * 32];
  __shared__ f16 Bs[2][128 * 32];

  const int lin = blockIdx.x;
  const int cpx = (int)gridDim.x >> 3;
  const int o = (lin & 7) * cpx + (lin >> 3);
  const int nt = o >> 2;
  const int mt = o & 3;
  const int m0 = mt * 128;
  const int n0 = nt * 128;
  const int tid = threadIdx.x;
  const int lane = tid & 63;
  const int wid = tid >> 6;
  const int wm = wid >> 1, wn = wid & 1;
  const int l15 = lane & 15, l4 = lane >> 4;

  floatx4 acc[4][4] = {};

  const int srow = tid >> 2;
  const int skp = (((tid & 3) ^ ((tid >> 3) & 3))) * 8;
  const f16* ap = A + (size_t)(m0 + srow) * 512 + skp;
  const f16* bp = B + (size_t)(n0 + srow) * 512 + skp;

  auto stage = [&](int buf, int k0) {
    f16* asl = As[buf] + tid * 8;
    f16* bsl = Bs[buf] + tid * 8;
    gload_lds16(ap + k0, asl);
    gload_lds16(ap + (size_t)64 * 512 + k0, asl + 2048);
    gload_lds16(bp + k0, bsl);
    gload_lds16(bp + (size_t)64 * 512 + k0, bsl + 2048);
  };

  const int rc = (l4 ^ ((l15 >> 1) & 3)) * 8;

  stage(0, 0);
  __syncthreads();
  int cur = 0;
  for (int k0 = 0; k0 < 512; k0 += 32) {
    if (k0 + 32 < 512) stage(cur ^ 1, k0 + 32);
    half8 af[4], bf[4];
#pragma unroll
    for (int mf = 0; mf < 4; ++mf)
      af[mf] = *(const half8*)(As[cur] + (wm * 64 + mf * 16 + l15) * 32 + rc);
#pragma unroll
    for (int nf = 0; nf < 4; ++nf)
      bf[nf] = *(const half8*)(Bs[cur] + (wn * 64 + nf * 16 + l15) * 32 + rc);
#pragma unroll
    for (int mf = 0; mf < 4; ++mf)
#pragma unroll
      for (int nf = 0; nf < 4; ++nf)
        acc[mf][nf] = __builtin_amdgcn_mfma_f32_16x16x32_f16(af[mf], bf[nf], acc[mf][nf], 0, 0, 0);
    __syncthreads();
    cur ^= 1;
  }

  const int mbase = m0 + wm * 64;
  const int nbase = n0 + wn * 64;
#pragma unroll
  for (int nf = 0; nf < 4; ++nf) {
    const int m2 = nbase + nf * 16 + l15;
    const int bb = m2 / 24576;
    const int rem = m2 - bb * 24576;
    const int t = rem >> 8;
    const int hw = rem & 255;
    float* op = Out + ((size_t)bb * 512 * 96 + t) * 256 + hw;
#pragma unroll
    for (int mf = 0; mf < 4; ++mf) {
#pragma unroll
      for (int j = 0; j < 4; ++j) {
        const int d = mbase + mf * 16 + l4 * 4 + j;
        __builtin_nontemporal_store(acc[mf][nf][j], op + (size_t)d * 24576);
      }
    }
  }
}

// ---------------------------------------------------------------------------
// Attention (r8/r10 structure): one 3-wave block per (nn, head); wave w
// handles m-blocks 2w, 2w+1. Softmax in base 2 (Q pre-scaled by 0.125*log2e).
// QKV rows m=(nn*96+t), cols: [0,512)=Q(biased,scaled) [512,1024)=K
// [1024,1536)=KL [1536,2048)=VL [2048,2560)=V (all row-major).
// V/VL transposed ONCE into LDS per block; all PV operands are 16B LDS reads.
// O stored via per-wave LDS transpose -> 2x16B/lane contiguous stores.
__global__ __launch_bounds__(192) void attn_kernel(
    const f16* __restrict__ QKV, f16* __restrict__ AO, int n0chunk) {
  const int nn = blockIdx.x >> 3;
  const int h = blockIdx.x & 7;
  const int tid = threadIdx.x;
  const int wid = tid >> 6;
  const int lane = tid & 63;
  const int l15 = lane & 15, l4 = lane >> 4;
  const int nglob = n0chunk + nn;
  const int bb = nglob >> 8, hw = nglob & 255;

  __shared__ __align__(16) f16 VTl[64][112];   // V^T  [dh][t], tail cols unused
  __shared__ __align__(16) f16 VLTl[64][112];  // VL^T [dh][t], cols 96..112 zeroed
  __shared__ __align__(16) float locS[3][16][4];
  __shared__ __align__(16) f16 pS[3][16][104];
  __shared__ __align__(16) f16 pS2[3][16][40];
  __shared__ __align__(16) f16 oesc[3][16][72];

  const f16* base = QKV + (size_t)nn * 96 * 2560;

  // ---- stage V^T, VL^T (coalesced global half8 reads -> scalar LDS writes)
#pragma unroll
  for (int it = 0; it < 4; ++it) {
    const int r = (tid >> 3) + it * 24;
    const int c0 = (tid & 7) * 8;
    half8 v  = *(const half8*)(base + (size_t)r * 2560 + 2048 + h * 64 + c0);
    half8 vl = *(const half8*)(base + (size_t)r * 2560 + 1536 + h * 64 + c0);
#pragma unroll
    for (int j = 0; j < 8; ++j) {
      VTl[c0 + j][r]  = v[j];
      VLTl[c0 + j][r] = vl[j];
    }
  }
  if (tid < 128) {  // zero VL^T tail cols (out-of-window reads hit these)
    half8 z = {};
    *(half8*)(&VLTl[tid >> 1][96 + (tid & 1) * 8]) = z;
  }

  // ---- K fragments (persistent, global): col t' = l15 + nf*16, k-contiguous
  half8 kb[6][2];
#pragma unroll
  for (int nf = 0; nf < 6; ++nf)
#pragma unroll
    for (int kg = 0; kg < 2; ++kg)
      kb[nf][kg] = *(const half8*)(base + (size_t)(nf * 16 + l15) * 2560 + 512 + h * 64 + kg * 32 + l4 * 8);

  __syncthreads();  // V^T/VL^T staged

  for (int mb = wid * 2; mb < wid * 2 + 2; ++mb) {
    const int t0 = mb * 16;
    const int tb = (t0 >= 2) ? (t0 - 2) : 0;  // even window base
    const int d0 = t0 - 1 - tb;               // -1 (t0==0) or +1

    // ---- Q and KL-window fragment loads (global)
    half8 aq[2], kl1[2], kl2[2];
    {
      int r1 = t0 - 1 + l15; if (r1 < 0) r1 = 0;
      int r2 = t0 + 1 + l15; if (r2 > 95) r2 = 95;
#pragma unroll
      for (int kg = 0; kg < 2; ++kg) {
        aq[kg]  = *(const half8*)(base + (size_t)(t0 + l15) * 2560 + h * 64 + kg * 32 + l4 * 8);
        kl1[kg] = *(const half8*)(base + (size_t)r1 * 2560 + 1024 + h * 64 + kg * 32 + l4 * 8);
        kl2[kg] = *(const half8*)(base + (size_t)r2 * 2560 + 1024 + h * 64 + kg * 32 + l4 * 8);
      }
    }

    // ---- S = Q K^T (16x96) and band windows SL1/SL2 (16x16 each)
    floatx4 s[6] = {};
    floatx4 sl1 = {}, sl2 = {};
#pragma unroll
    for (int nf = 0; nf < 6; ++nf)
#pragma unroll
      for (int kg = 0; kg < 2; ++kg)
        s[nf] = __builtin_amdgcn_mfma_f32_16x16x32_f16(aq[kg], kb[nf][kg], s[nf], 0, 0, 0);
#pragma unroll
    for (int kg = 0; kg < 2; ++kg) {
      sl1 = __builtin_amdgcn_mfma_f32_16x16x32_f16(aq[kg], kl1[kg], sl1, 0, 0, 0);
      sl2 = __builtin_amdgcn_mfma_f32_16x16x32_f16(aq[kg], kl2[kg], sl2, 0, 0, 0);
    }

    // ---- PV operand loads from LDS (16B contiguous)
    half8 vb[4][3], vlb[4];
#pragma unroll
    for (int nf = 0; nf < 4; ++nf) {
#pragma unroll
      for (int kg = 0; kg < 3; ++kg)
        vb[nf][kg] = *(const half8*)(&VTl[nf * 16 + l15][kg * 32 + l4 * 8]);
      vlb[nf] = load_h8u(&VLTl[nf * 16 + l15][tb + l4 * 8]);
    }

    // ---- zero pS2, extract band logits -> locS
    {
      half8 z = {};
      f16* pz = &pS2[wid][0][0];
      *(half8*)(pz + lane * 8) = z;
      if (lane < 16) *(half8*)(pz + 512 + lane * 8) = z;
    }
#pragma unroll
    for (int j = 0; j < 4; ++j) {
      const int r = l4 * 4 + j;
      const int s1i = l15 - r;
      if (s1i >= 0 && s1i < 3) locS[wid][r][s1i] = sl1[j];
      const int s2i = l15 + 2 - r;
      if (l15 >= 14 && s2i >= 0 && s2i < 3) locS[wid][r][s2i] = sl2[j];
    }
    __syncthreads();

    // ---- softmax per row, base-2 (logits pre-scaled by log2e via QSCALE)
#pragma unroll
    for (int j = 0; j < 4; ++j) {
      const int row = l4 * 4 + j;
      float sv[6];
#pragma unroll
      for (int nf = 0; nf < 6; ++nf) sv[nf] = s[nf][j];
      float mx = sv[0];
#pragma unroll
      for (int nf = 1; nf < 6; ++nf) mx = fmaxf(mx, sv[nf]);
      for (int off = 1; off < 16; off <<= 1) mx = fmaxf(mx, __shfl_xor(mx, off, 64));
      const float l0 = (t0 + row >= 1)  ? locS[wid][row][0] : -__builtin_inff();
      const float l1 = locS[wid][row][1];
      const float l2 = (t0 + row <= 94) ? locS[wid][row][2] : -__builtin_inff();
      mx = fmaxf(mx, fmaxf(l0, fmaxf(l1, l2)));
      float e[6], sum = 0.f;
#pragma unroll
      for (int nf = 0; nf < 6; ++nf) {
        e[nf] = exp2f(sv[nf] - mx);
        sum += e[nf];
      }
      for (int off = 1; off < 16; off <<= 1) sum += __shfl_xor(sum, off, 64);
      const float e0 = exp2f(l0 - mx), e1 = exp2f(l1 - mx), e2 = exp2f(l2 - mx);
      sum += e0 + e1 + e2;
      const float rd = 1.0f / sum;
#pragma unroll
      for (int nf = 0; nf < 6; ++nf) pS[wid][row][nf * 16 + l15] = (f16)(e[nf] * rd);
      if (l15 < 3) {
        const int w = row + l15 + d0;
        const float ev = (l15 == 0) ? e0 : ((l15 == 1) ? e1 : e2);
        if (w >= 0) pS2[wid][row][w] = (f16)(ev * rd);
      }
    }
    __syncthreads();

    // ---- O = P @ V  +  P2 @ VL-window
    floatx4 o[4] = {};
    half8 pfr[3];
#pragma unroll
    for (int kg = 0; kg < 3; ++kg)
      pfr[kg] = *(const half8*)(&pS[wid][l15][kg * 32 + l4 * 8]);
    half8 pf2 = *(const half8*)(&pS2[wid][l15][l4 * 8]);
#pragma unroll
    for (int nf = 0; nf < 4; ++nf) {
#pragma unroll
      for (int kg = 0; kg < 3; ++kg)
        o[nf] = __builtin_amdgcn_mfma_f32_16x16x32_f16(pfr[kg], vb[nf][kg], o[nf], 0, 0, 0);
      o[nf] = __builtin_amdgcn_mfma_f32_16x16x32_f16(pf2, vlb[nf], o[nf], 0, 0, 0);
    }

    // ---- store via per-wave transpose: 2x16B contiguous per lane
#pragma unroll
    for (int nf = 0; nf < 4; ++nf)
#pragma unroll
      for (int j = 0; j < 4; ++j)
        oesc[wid][l4 * 4 + j][nf * 16 + l15] = (f16)o[nf][j];
    asm volatile("s_waitcnt lgkmcnt(0)" ::: "memory");
    {
      const int rrow = lane >> 2;
      const int rcg  = lane & 3;
      half8 v0 = *(const half8*)(&oesc[wid][rrow][rcg * 16]);
      half8 v1 = *(const half8*)(&oesc[wid][rrow][rcg * 16 + 8]);
      asm volatile("" ::: "memory");
      f16* dst = AO + ((size_t)(bb * 96 + t0 + rrow) * 256 + hw) * 512 + h * 64 + rcg * 16;
      *(half8*)dst = v0;
      *(half8*)(dst + 8) = v1;
    }
  }
}

// ---------------------------------------------------------------------------
extern "C" void kernel_launch(void* const* d_in, const int* in_sizes, int n_in,
                              void* d_out, int out_size, void* d_ws, size_t ws_size,
                              hipStream_t stream) {
  (void)in_sizes; (void)n_in; (void)out_size;
  const float* x     = (const float*)d_in[0];
  const float* gamma = (const float*)d_in[1];
  const float* beta  = (const float*)d_in[2];
  const float* Wq    = (const float*)d_in[3];
  const float* Wk    = (const float*)d_in[4];
  const float* Wv    = (const float*)d_in[5];
  const float* Wkl   = (const float*)d_in[6];
  const float* Wvl   = (const float*)d_in[7];
  const float* Wo    = (const float*)d_in[8];
  const float* qb    = (const float*)d_in[9];
  float* out = (float*)d_out;

  char* ws = (char*)d_ws;
  size_t off = 0;
  auto alloc = [&](size_t bytes) -> void* {
    void* p = ws + off;
    off += (bytes + 255) & ~(size_t)255;
    return p;
  };
  f16* XN   = (f16*)alloc((size_t)MTOT * 512 * 2);
  f16* AO   = (f16*)alloc((size_t)MTOT * 512 * 2);
  f16* WQKV = (f16*)alloc((size_t)2560 * 512 * 2);
  f16* WOh  = (f16*)alloc((size_t)512 * 512 * 2);
  // chunking over n (512 total) to bound workspace; need cn*96 % 256 == 0
  int cn = 512;
  while (cn > 32 && off + (size_t)cn * 96 * 2560 * 2 + 256 > ws_size)
    cn >>= 1;
  f16* QKVc = (f16*)alloc((size_t)cn * 96 * 2560 * 2);

  wconv_kernel<<<5120, 256, 0, stream>>>(Wq, Wk, Wv, Wkl, Wvl, Wo, WQKV, WOh);
  ln_kernel<<<768, 256, 0, stream>>>(x, gamma, beta, XN);

  const int nch = 512 / cn;
  for (int c = 0; c < nch; ++c) {
    const int mtiles = (cn * 96) / 256;
    gemmA_kernel<<<mtiles * 10, 512, 0, stream>>>(XN + (size_t)c * cn * 96 * 512,
                                                  WQKV, QKVc, qb);
    attn_kernel<<<cn * 8, 192, 0, stream>>>(QKVc, AO, c * cn);
  }
  gemmO_kernel<<<1536, 256, 0, stream>>>(WOh, AO, out);
}

// Round 18
// 381.340 us; speedup vs baseline: 1.1060x; 1.0091x over previous
//
#include <hip/hip_runtime.h>
#include <hip/hip_fp16.h>
#include <cstdint>
#include <cstddef>

typedef _Float16 f16;
typedef _Float16 half8 __attribute__((ext_vector_type(8)));
typedef _Float16 half4v __attribute__((ext_vector_type(4)));
typedef float floatx4 __attribute__((ext_vector_type(4)));

#define MTOT 49152  // B*T*HW rows total (=2*96*256), also = N_TOT*T
#define QSCALE 0.180336880111120426f  // 0.125 * log2(e): folds softmax base-2

// ---------------------------------------------------------------------------
// async global->LDS, 16B per lane
__device__ __forceinline__ void gload_lds16(const f16* g, f16* l) {
  __builtin_amdgcn_global_load_lds((const __attribute__((address_space(1))) void*)g,
                                   (__attribute__((address_space(3))) void*)l, 16, 0, 0);
}

// alignment-tolerant 16B load (addr may be only 4B-aligned)
__device__ __forceinline__ half8 load_h8u(const f16* p) {
  half8 v;
  __builtin_memcpy(&v, p, 16);
  return v;
}

// ---------------------------------------------------------------------------
// Convert weights fp32 -> f16. WQKV rows: [0,512)=Wq [512,1024)=Wk
// [1024,1536)=Wkl [1536,2048)=Wvl [2048,2560)=Wv.  WO separate.
__global__ __launch_bounds__(256) void wconv_kernel(
    const float* __restrict__ Wq, const float* __restrict__ Wk,
    const float* __restrict__ Wv, const float* __restrict__ Wkl,
    const float* __restrict__ Wvl, const float* __restrict__ Wo,
    f16* __restrict__ WQKV, f16* __restrict__ WO) {
  int idx = blockIdx.x * 256 + threadIdx.x;
  if (idx < 2560 * 512) {
    int row = idx >> 9;
    int col = idx & 511;
    int seg = row >> 9;
    int r = row & 511;
    const float* src;
    switch (seg) {
      case 0: src = Wq; break;
      case 1: src = Wk; break;
      case 2: src = Wkl; break;
      case 3: src = Wvl; break;
      default: src = Wv; break;
    }
    WQKV[idx] = (f16)src[r * 512 + col];
  }
  if (idx < 512 * 512) WO[idx] = (f16)Wo[idx];
}

// ---------------------------------------------------------------------------
// LayerNorm over D. x layout (B=2, D=512, T=96, HW=256).
// Output XN f16 row-major [m][512], m = (b*256+hw)*96 + t.
// x register-cached; output via 64KB LDS transpose tile (chunk-XOR both
// sides) -> 4-lane groups store 64B contiguous XN segments (r16, -7us).
__global__ __launch_bounds__(256) void ln_kernel(
    const float* __restrict__ x, const float* __restrict__ gamma,
    const float* __restrict__ beta, f16* __restrict__ XN) {
  const int hwg = blockIdx.x & 3;
  const int t   = (blockIdx.x >> 2) % 96;
  const int b   = blockIdx.x / (4 * 96);
  const int lhw = threadIdx.x & 63;
  const int dg  = threadIdx.x >> 6;
  const float* xp = x + (size_t)b * 512 * 24576 + (size_t)t * 256 +
                    (hwg * 64 + lhw) + (size_t)dg * 128 * 24576;

  float v[128];
  float s = 0.f, s2 = 0.f;
#pragma unroll
  for (int j = 0; j < 128; ++j) {
    float u = xp[(size_t)j * 24576];
    v[j] = u;
    s += u;
    s2 += u * u;
  }
  __shared__ float S1[4][64], S2[4][64];
  __shared__ __align__(16) f16 XT[64][512];  // transpose tile, 64KB
  S1[dg][lhw] = s;
  S2[dg][lhw] = s2;
  __syncthreads();
  s  = S1[0][lhw] + S1[1][lhw] + S1[2][lhw] + S1[3][lhw];
  s2 = S2[0][lhw] + S2[1][lhw] + S2[2][lhw] + S2[3][lhw];
  const float mean = s * (1.f / 512.f);
  float var = s2 * (1.f / 512.f) - mean * mean;
  var = fmaxf(var, 0.f);
  const float rstd = rsqrtf(var + 1e-6f);

#pragma unroll
  for (int ic = 0; ic < 16; ++ic) {
    const int c = dg * 16 + ic;
    const int slot = c ^ (lhw & 7);
    half8 buf;
#pragma unroll
    for (int j = 0; j < 8; ++j) {
      const int d = c * 8 + j;
      buf[j] = (f16)((v[ic * 8 + j] - mean) * rstd * gamma[d] + beta[d]);
    }
    *(half8*)(&XT[lhw][slot * 8]) = buf;
  }
  __syncthreads();

  const int rr = threadIdx.x >> 2;
  const int seg = threadIdx.x & 3;
  const int n = b * 256 + hwg * 64 + rr;
  f16* outp = XN + ((size_t)n * 96 + t) * 512;
#pragma unroll
  for (int i = 0; i < 16; ++i) {
    const int c = i * 4 + seg;
    const int slot = c ^ (rr & 7);
    half8 w = *(const half8*)(&XT[rr][slot * 8]);
    *(half8*)(outp + c * 8) = w;
  }
}

// ---------------------------------------------------------------------------
// GEMM A (projections): C[m][n] = sum_k A[m][k]*B[n][k], K=512, N=2560.
// 256x256 tile, BK=64, 512 threads = 8 waves (2m x 4n), wave tile 128x64.
// r7/r13 schedule (best measured: 172us). setprio (T5), XOR swizzle (T2).
// Epilogue: per-wave LDS transpose -> 2x16B/lane plain stores; Q cols get
// +bias and *QSCALE.
__global__ __launch_bounds__(512, 2) void gemmA_kernel(
    const f16* __restrict__ A, const f16* __restrict__ B,
    f16* __restrict__ Cqkv, const float* __restrict__ qbias) {
  __shared__ f16 LA[2][256 * 64];
  __shared__ f16 LB[2][256 * 64];
  __shared__ __align__(16) f16 esc[8][16][72];

  const int lin = blockIdx.x;
  const int cpx = (int)gridDim.x >> 3;
  const int swz = (lin & 7) * cpx + (lin >> 3);
  const int o = ((gridDim.x & 7) == 0) ? swz : lin;  // bijective only if %8==0
  const int mt = o / 10;
  const int nt = o % 10;
  const int m0 = mt * 256;
  const int n0 = nt * 256;

  const int tid = threadIdx.x;
  const int wid = tid >> 6;
  const int lane = tid & 63;
  const int wm = wid >> 2;  // 0..1
  const int wn = wid & 3;   // 0..3
  const int l15 = lane & 15, l4 = lane >> 4;

  const int srow = tid >> 3;
  const int scol = ((tid & 7) ^ (srow & 7)) * 8;
  const f16* Abase = A + (size_t)(m0 + srow) * 512 + scol;
  const f16* Bbase = B + (size_t)(n0 + srow) * 512 + scol;

  const int cks0 = ((l4) ^ (l15 & 7)) * 8;
  const int cks1 = ((4 + l4) ^ (l15 & 7)) * 8;
  const int arow = wm * 128 + l15;
  const int brow = wn * 64 + l15;

  floatx4 acc[8][4] = {};
  half8 a_f[4][2];
  half8 b_f[4][2];

  auto stageH = [&](int slot, int kt, int mat, int h) {
    const f16* g = (mat ? Bbase : Abase) + kt * 64 + (size_t)(h * 128) * 512;
    f16* l = (mat ? LB[slot] : LA[slot]) + h * 8192 + tid * 8;
    gload_lds16(g, l);
    gload_lds16(g + (size_t)64 * 512, l + 4096);
  };

  stageH(0, 0, 0, 0); stageH(0, 0, 0, 1);
  stageH(0, 0, 1, 0); stageH(0, 0, 1, 1);
  stageH(1, 1, 0, 0);
  asm volatile("s_waitcnt vmcnt(2)" ::: "memory");
  __builtin_amdgcn_s_barrier();

#pragma unroll
  for (int kt = 0; kt < 8; ++kt) {
    const f16* As = LA[kt & 1];
    const f16* Bs = LB[kt & 1];
    const int nsl = (kt + 1) & 1;

#pragma unroll
    for (int mf2 = 0; mf2 < 4; ++mf2) {
      a_f[mf2][0] = *(const half8*)(As + (arow + mf2 * 16) * 64 + cks0);
      a_f[mf2][1] = *(const half8*)(As + (arow + mf2 * 16) * 64 + cks1);
    }
#pragma unroll
    for (int nf = 0; nf < 2; ++nf) {
      b_f[nf][0] = *(const half8*)(Bs + (brow + nf * 16) * 64 + cks0);
      b_f[nf][1] = *(const half8*)(Bs + (brow + nf * 16) * 64 + cks1);
    }
    if (kt + 1 < 8) stageH(nsl, kt + 1, 0, 1);
    __builtin_amdgcn_s_barrier();
    __builtin_amdgcn_s_setprio(1);
#pragma unroll
    for (int mf2 = 0; mf2 < 4; ++mf2)
#pragma unroll
      for (int nf2 = 0; nf2 < 2; ++nf2)
#pragma unroll
        for (int ks = 0; ks < 2; ++ks)
          acc[mf2][nf2] = __builtin_amdgcn_mfma_f32_16x16x32_f16(
              a_f[mf2][ks], b_f[nf2][ks], acc[mf2][nf2], 0, 0, 0);
    __builtin_amdgcn_s_setprio(0);
    __builtin_amdgcn_s_barrier();

#pragma unroll
    for (int nf = 2; nf < 4; ++nf) {
      b_f[nf][0] = *(const half8*)(Bs + (brow + nf * 16) * 64 + cks0);
      b_f[nf][1] = *(const half8*)(Bs + (brow + nf * 16) * 64 + cks1);
    }
    if (kt + 1 < 8) stageH(nsl, kt + 1, 1, 0);
    __builtin_amdgcn_s_barrier();
    __builtin_amdgcn_s_setprio(1);
#pragma unroll
    for (int mf2 = 0; mf2 < 4; ++mf2)
#pragma unroll
      for (int nf2 = 0; nf2 < 2; ++nf2)
#pragma unroll
        for (int ks = 0; ks < 2; ++ks)
          acc[mf2][2 + nf2] = __builtin_amdgcn_mfma_f32_16x16x32_f16(
              a_f[mf2][ks], b_f[2 + nf2][ks], acc[mf2][2 + nf2], 0, 0, 0);
    __builtin_amdgcn_s_setprio(0);
    __builtin_amdgcn_s_barrier();

#pragma unroll
    for (int mf2 = 0; mf2 < 4; ++mf2) {
      a_f[mf2][0] = *(const half8*)(As + (arow + 64 + mf2 * 16) * 64 + cks0);
      a_f[mf2][1] = *(const half8*)(As + (arow + 64 + mf2 * 16) * 64 + cks1);
    }
    if (kt + 1 < 8) stageH(nsl, kt + 1, 1, 1);
    __builtin_amdgcn_s_barrier();
    __builtin_amdgcn_s_setprio(1);
#pragma unroll
    for (int mf2 = 0; mf2 < 4; ++mf2)
#pragma unroll
      for (int nf2 = 0; nf2 < 2; ++nf2)
#pragma unroll
        for (int ks = 0; ks < 2; ++ks)
          acc[4 + mf2][nf2] = __builtin_amdgcn_mfma_f32_16x16x32_f16(
              a_f[mf2][ks], b_f[nf2][ks], acc[4 + mf2][nf2], 0, 0, 0);
    __builtin_amdgcn_s_setprio(0);
    __builtin_amdgcn_s_barrier();

    if (kt + 2 < 8) stageH(kt & 1, kt + 2, 0, 0);
    __builtin_amdgcn_s_barrier();
    __builtin_amdgcn_s_setprio(1);
#pragma unroll
    for (int mf2 = 0; mf2 < 4; ++mf2)
#pragma unroll
      for (int nf2 = 0; nf2 < 2; ++nf2)
#pragma unroll
        for (int ks = 0; ks < 2; ++ks)
          acc[4 + mf2][2 + nf2] = __builtin_amdgcn_mfma_f32_16x16x32_f16(
              a_f[mf2][ks], b_f[2 + nf2][ks], acc[4 + mf2][2 + nf2], 0, 0, 0);
    __builtin_amdgcn_s_setprio(0);
    if (kt < 6) {
      asm volatile("s_waitcnt vmcnt(2)" ::: "memory");
    } else if (kt == 6) {
      asm volatile("s_waitcnt vmcnt(0)" ::: "memory");
    }
    __builtin_amdgcn_s_barrier();
  }

  float bias[4], scl[4];
#pragma unroll
  for (int nf = 0; nf < 4; ++nf) {
    const int n = n0 + wn * 64 + nf * 16 + l15;
    const bool isq = (n < 512);
    bias[nf] = isq ? qbias[n] : 0.0f;
    scl[nf]  = isq ? QSCALE : 1.0f;
  }
  const int rrow = lane >> 2;
  const int rcg  = lane & 3;
#pragma unroll
  for (int mf = 0; mf < 8; ++mf) {
#pragma unroll
    for (int nf = 0; nf < 4; ++nf)
#pragma unroll
      for (int j = 0; j < 4; ++j)
        esc[wid][l4 * 4 + j][nf * 16 + l15] = (f16)((acc[mf][nf][j] + bias[nf]) * scl[nf]);
    asm volatile("s_waitcnt lgkmcnt(0)" ::: "memory");
    half8 v0 = *(const half8*)(&esc[wid][rrow][rcg * 16]);
    half8 v1 = *(const half8*)(&esc[wid][rrow][rcg * 16 + 8]);
    asm volatile("" ::: "memory");
    f16* dst = Cqkv + (size_t)(m0 + wm * 128 + mf * 16 + rrow) * 2560 + n0 + wn * 64 + rcg * 16;
    *(half8*)dst = v0;
    *(half8*)(dst + 8) = v1;
  }
}

// ---------------------------------------------------------------------------
// Output GEMM (Wo), 256x256 8-phase (gemmA loop body, r17): M=512 (2 m-tiles),
// N=49152 (192 n-tiles); n-tile-major order (AO panels streamed once; WOh is
// 0.5MB -> L2-resident). Epilogue: fp32 out in (B,D,T,HW) layout, NT stores
// (16-lane hw-contiguous 64B segments).
__global__ __launch_bounds__(512, 2) void gemmO256_kernel(
    const f16* __restrict__ A, const f16* __restrict__ B,
    float* __restrict__ Out) {
  __shared__ f16 LA[2][256 * 64];
  __shared__ f16 LB[2][256 * 64];

  const int lin = blockIdx.x;
  const int cpx = (int)gridDim.x >> 3;  // 384/8 = 48
  const int o = (lin & 7) * cpx + (lin >> 3);
  const int mt = o & 1;
  const int nt = o >> 1;
  const int m0 = mt * 256;
  const int n0 = nt * 256;

  const int tid = threadIdx.x;
  const int wid = tid >> 6;
  const int lane = tid & 63;
  const int wm = wid >> 2;
  const int wn = wid & 3;
  const int l15 = lane & 15, l4 = lane >> 4;

  const int srow = tid >> 3;
  const int scol = ((tid & 7) ^ (srow & 7)) * 8;
  const f16* Abase = A + (size_t)(m0 + srow) * 512 + scol;
  const f16* Bbase = B + (size_t)(n0 + srow) * 512 + scol;

  const int cks0 = ((l4) ^ (l15 & 7)) * 8;
  const int cks1 = ((4 + l4) ^ (l15 & 7)) * 8;
  const int arow = wm * 128 + l15;
  const int brow = wn * 64 + l15;

  floatx4 acc[8][4] = {};
  half8 a_f[4][2];
  half8 b_f[4][2];

  auto stageH = [&](int slot, int kt, int mat, int h) {
    const f16* g = (mat ? Bbase : Abase) + kt * 64 + (size_t)(h * 128) * 512;
    f16* l = (mat ? LB[slot] : LA[slot]) + h * 8192 + tid * 8;
    gload_lds16(g, l);
    gload_lds16(g + (size_t)64 * 512, l + 4096);
  };

  stageH(0, 0, 0, 0); stageH(0, 0, 0, 1);
  stageH(0, 0, 1, 0); stageH(0, 0, 1, 1);
  stageH(1, 1, 0, 0);
  asm volatile("s_waitcnt vmcnt(2)" ::: "memory");
  __builtin_amdgcn_s_barrier();

#pragma unroll
  for (int kt = 0; kt < 8; ++kt) {
    const f16* As = LA[kt & 1];
    const f16* Bs = LB[kt & 1];
    const int nsl = (kt + 1) & 1;

#pragma unroll
    for (int mf2 = 0; mf2 < 4; ++mf2) {
      a_f[mf2][0] = *(const half8*)(As + (arow + mf2 * 16) * 64 + cks0);
      a_f[mf2][1] = *(const half8*)(As + (arow + mf2 * 16) * 64 + cks1);
    }
#pragma unroll
    for (int nf = 0; nf < 2; ++nf) {
      b_f[nf][0] = *(const half8*)(Bs + (brow + nf * 16) * 64 + cks0);
      b_f[nf][1] = *(const half8*)(Bs + (brow + nf * 16) * 64 + cks1);
    }
    if (kt + 1 < 8) stageH(nsl, kt + 1, 0, 1);
    __builtin_amdgcn_s_barrier();
    __builtin_amdgcn_s_setprio(1);
#pragma unroll
    for (int mf2 = 0; mf2 < 4; ++mf2)
#pragma unroll
      for (int nf2 = 0; nf2 < 2; ++nf2)
#pragma unroll
        for (int ks = 0; ks < 2; ++ks)
          acc[mf2][nf2] = __builtin_amdgcn_mfma_f32_16x16x32_f16(
              a_f[mf2][ks], b_f[nf2][ks], acc[mf2][nf2], 0, 0, 0);
    __builtin_amdgcn_s_setprio(0);
    __builtin_amdgcn_s_barrier();

#pragma unroll
    for (int nf = 2; nf < 4; ++nf) {
      b_f[nf][0] = *(const half8*)(Bs + (brow + nf * 16) * 64 + cks0);
      b_f[nf][1] = *(const half8*)(Bs + (brow + nf * 16) * 64 + cks1);
    }
    if (kt + 1 < 8) stageH(nsl, kt + 1, 1, 0);
    __builtin_amdgcn_s_barrier();
    __builtin_amdgcn_s_setprio(1);
#pragma unroll
    for (int mf2 = 0; mf2 < 4; ++mf2)
#pragma unroll
      for (int nf2 = 0; nf2 < 2; ++nf2)
#pragma unroll
        for (int ks = 0; ks < 2; ++ks)
          acc[mf2][2 + nf2] = __builtin_amdgcn_mfma_f32_16x16x32_f16(
              a_f[mf2][ks], b_f[2 + nf2][ks], acc[mf2][2 + nf2], 0, 0, 0);
    __builtin_amdgcn_s_setprio(0);
    __builtin_amdgcn_s_barrier();

#pragma unroll
    for (int mf2 = 0; mf2 < 4; ++mf2) {
      a_f[mf2][0] = *(const half8*)(As + (arow + 64 + mf2 * 16) * 64 + cks0);
      a_f[mf2][1] = *(const half8*)(As + (arow + 64 + mf2 * 16) * 64 + cks1);
    }
    if (kt + 1 < 8) stageH(nsl, kt + 1, 1, 1);
    __builtin_amdgcn_s_barrier();
    __builtin_amdgcn_s_setprio(1);
#pragma unroll
    for (int mf2 = 0; mf2 < 4; ++mf2)
#pragma unroll
      for (int nf2 = 0; nf2 < 2; ++nf2)
#pragma unroll
        for (int ks = 0; ks < 2; ++ks)
          acc[4 + mf2][nf2] = __builtin_amdgcn_mfma_f32_16x16x32_f16(
              a_f[mf2][ks], b_f[nf2][ks], acc[4 + mf2][nf2], 0, 0, 0);
    __builtin_amdgcn_s_setprio(0);
    __builtin_amdgcn_s_barrier();

    if (kt + 2 < 8) stageH(kt & 1, kt + 2, 0, 0);
    __builtin_amdgcn_s_barrier();
    __builtin_amdgcn_s_setprio(1);
#pragma unroll
    for (int mf2 = 0; mf2 < 4; ++mf2)
#pragma unroll
      for (int nf2 = 0; nf2 < 2; ++nf2)
#pragma unroll
        for (int ks = 0; ks < 2; ++ks)
          acc[4 + mf2][2 + nf2] = __builtin_amdgcn_mfma_f32_16x16x32_f16(
              a_f[mf2][ks], b_f[2 + nf2][ks], acc[4 + mf2][2 + nf2], 0, 0, 0);
    __builtin_amdgcn_s_setprio(0);
    if (kt < 6) {
      asm volatile("s_waitcnt vmcnt(2)" ::: "memory");
    } else if (kt == 6) {
      asm volatile("s_waitcnt vmcnt(0)" ::: "memory");
    }
    __builtin_amdgcn_s_barrier();
  }

  // epilogue: fp32 scatter, d = m index, m2 = n index
#pragma unroll
  for (int nf = 0; nf < 4; ++nf) {
    const int m2 = n0 + wn * 64 + nf * 16 + l15;
    const int bb = m2 / 24576;
    const int rem = m2 - bb * 24576;
    const int t = rem >> 8;
    const int hw = rem & 255;
    float* op = Out + ((size_t)bb * 512 * 96 + t) * 256 + hw;
#pragma unroll
    for (int mf = 0; mf < 8; ++mf) {
#pragma unroll
      for (int j = 0; j < 4; ++j) {
        const int d = m0 + wm * 128 + mf * 16 + l4 * 4 + j;
        __builtin_nontemporal_store(acc[mf][nf][j], op + (size_t)d * 24576);
      }
    }
  }
}

// ---------------------------------------------------------------------------
// Attention (r8/r10 structure): one 3-wave block per (nn, head); wave w
// handles m-blocks 2w, 2w+1. Softmax in base 2 (Q pre-scaled by 0.125*log2e).
// QKV rows m=(nn*96+t), cols: [0,512)=Q(biased,scaled) [512,1024)=K
// [1024,1536)=KL [1536,2048)=VL [2048,2560)=V (all row-major).
// V/VL transposed ONCE into LDS per block; all PV operands are 16B LDS reads.
// O stored via per-wave LDS transpose -> 2x16B/lane contiguous stores.
__global__ __launch_bounds__(192) void attn_kernel(
    const f16* __restrict__ QKV, f16* __restrict__ AO, int n0chunk) {
  const int nn = blockIdx.x >> 3;
  const int h = blockIdx.x & 7;
  const int tid = threadIdx.x;
  const int wid = tid >> 6;
  const int lane = tid & 63;
  const int l15 = lane & 15, l4 = lane >> 4;
  const int nglob = n0chunk + nn;
  const int bb = nglob >> 8, hw = nglob & 255;

  __shared__ __align__(16) f16 VTl[64][112];   // V^T  [dh][t], tail cols unused
  __shared__ __align__(16) f16 VLTl[64][112];  // VL^T [dh][t], cols 96..112 zeroed
  __shared__ __align__(16) float locS[3][16][4];
  __shared__ __align__(16) f16 pS[3][16][104];
  __shared__ __align__(16) f16 pS2[3][16][40];
  __shared__ __align__(16) f16 oesc[3][16][72];

  const f16* base = QKV + (size_t)nn * 96 * 2560;

  // ---- stage V^T, VL^T (coalesced global half8 reads -> scalar LDS writes)
#pragma unroll
  for (int it = 0; it < 4; ++it) {
    const int r = (tid >> 3) + it * 24;
    const int c0 = (tid & 7) * 8;
    half8 v  = *(const half8*)(base + (size_t)r * 2560 + 2048 + h * 64 + c0);
    half8 vl = *(const half8*)(base + (size_t)r * 2560 + 1536 + h * 64 + c0);
#pragma unroll
    for (int j = 0; j < 8; ++j) {
      VTl[c0 + j][r]  = v[j];
      VLTl[c0 + j][r] = vl[j];
    }
  }
  if (tid < 128) {  // zero VL^T tail cols (out-of-window reads hit these)
    half8 z = {};
    *(half8*)(&VLTl[tid >> 1][96 + (tid & 1) * 8]) = z;
  }

  // ---- K fragments (persistent, global): col t' = l15 + nf*16, k-contiguous
  half8 kb[6][2];
#pragma unroll
  for (int nf = 0; nf < 6; ++nf)
#pragma unroll
    for (int kg = 0; kg < 2; ++kg)
      kb[nf][kg] = *(const half8*)(base + (size_t)(nf * 16 + l15) * 2560 + 512 + h * 64 + kg * 32 + l4 * 8);

  __syncthreads();  // V^T/VL^T staged

  for (int mb = wid * 2; mb < wid * 2 + 2; ++mb) {
    const int t0 = mb * 16;
    const int tb = (t0 >= 2) ? (t0 - 2) : 0;  // even window base
    const int d0 = t0 - 1 - tb;               // -1 (t0==0) or +1

    // ---- Q and KL-window fragment loads (global)
    half8 aq[2], kl1[2], kl2[2];
    {
      int r1 = t0 - 1 + l15; if (r1 < 0) r1 = 0;
      int r2 = t0 + 1 + l15; if (r2 > 95) r2 = 95;
#pragma unroll
      for (int kg = 0; kg < 2; ++kg) {
        aq[kg]  = *(const half8*)(base + (size_t)(t0 + l15) * 2560 + h * 64 + kg * 32 + l4 * 8);
        kl1[kg] = *(const half8*)(base + (size_t)r1 * 2560 + 1024 + h * 64 + kg * 32 + l4 * 8);
        kl2[kg] = *(const half8*)(base + (size_t)r2 * 2560 + 1024 + h * 64 + kg * 32 + l4 * 8);
      }
    }

    // ---- S = Q K^T (16x96) and band windows SL1/SL2 (16x16 each)
    floatx4 s[6] = {};
    floatx4 sl1 = {}, sl2 = {};
#pragma unroll
    for (int nf = 0; nf < 6; ++nf)
#pragma unroll
      for (int kg = 0; kg < 2; ++kg)
        s[nf] = __builtin_amdgcn_mfma_f32_16x16x32_f16(aq[kg], kb[nf][kg], s[nf], 0, 0, 0);
#pragma unroll
    for (int kg = 0; kg < 2; ++kg) {
      sl1 = __builtin_amdgcn_mfma_f32_16x16x32_f16(aq[kg], kl1[kg], sl1, 0, 0, 0);
      sl2 = __builtin_amdgcn_mfma_f32_16x16x32_f16(aq[kg], kl2[kg], sl2, 0, 0, 0);
    }

    // ---- PV operand loads from LDS (16B contiguous)
    half8 vb[4][3], vlb[4];
#pragma unroll
    for (int nf = 0; nf < 4; ++nf) {
#pragma unroll
      for (int kg = 0; kg < 3; ++kg)
        vb[nf][kg] = *(const half8*)(&VTl[nf * 16 + l15][kg * 32 + l4 * 8]);
      vlb[nf] = load_h8u(&VLTl[nf * 16 + l15][tb + l4 * 8]);
    }

    // ---- zero pS2, extract band logits -> locS
    {
      half8 z = {};
      f16* pz = &pS2[wid][0][0];
      *(half8*)(pz + lane * 8) = z;
      if (lane < 16) *(half8*)(pz + 512 + lane * 8) = z;
    }
#pragma unroll
    for (int j = 0; j < 4; ++j) {
      const int r = l4 * 4 + j;
      const int s1i = l15 - r;
      if (s1i >= 0 && s1i < 3) locS[wid][r][s1i] = sl1[j];
      const int s2i = l15 + 2 - r;
      if (l15 >= 14 && s2i >= 0 && s2i < 3) locS[wid][r][s2i] = sl2[j];
    }
    __syncthreads();

    // ---- softmax per row, base-2 (logits pre-scaled by log2e via QSCALE)
#pragma unroll
    for (int j = 0; j < 4; ++j) {
      const int row = l4 * 4 + j;
      float sv[6];
#pragma unroll
      for (int nf = 0; nf < 6; ++nf) sv[nf] = s[nf][j];
      float mx = sv[0];
#pragma unroll
      for (int nf = 1; nf < 6; ++nf) mx = fmaxf(mx, sv[nf]);
      for (int off = 1; off < 16; off <<= 1) mx = fmaxf(mx, __shfl_xor(mx, off, 64));
      const float l0 = (t0 + row >= 1)  ? locS[wid][row][0] : -__builtin_inff();
      const float l1 = locS[wid][row][1];
      const float l2 = (t0 + row <= 94) ? locS[wid][row][2] : -__builtin_inff();
      mx = fmaxf(mx, fmaxf(l0, fmaxf(l1, l2)));
      float e[6], sum = 0.f;
#pragma unroll
      for (int nf = 0; nf < 6; ++nf) {
        e[nf] = exp2f(sv[nf] - mx);
        sum += e[nf];
      }
      for (int off = 1; off < 16; off <<= 1) sum += __shfl_xor(sum, off, 64);
      const float e0 = exp2f(l0 - mx), e1 = exp2f(l1 - mx), e2 = exp2f(l2 - mx);
      sum += e0 + e1 + e2;
      const float rd = 1.0f / sum;
#pragma unroll
      for (int nf = 0; nf < 6; ++nf) pS[wid][row][nf * 16 + l15] = (f16)(e[nf] * rd);
      if (l15 < 3) {
        const int w = row + l15 + d0;
        const float ev = (l15 == 0) ? e0 : ((l15 == 1) ? e1 : e2);
        if (w >= 0) pS2[wid][row][w] = (f16)(ev * rd);
      }
    }
    __syncthreads();

    // ---- O = P @ V  +  P2 @ VL-window
    floatx4 o[4] = {};
    half8 pfr[3];
#pragma unroll
    for (int kg = 0; kg < 3; ++kg)
      pfr[kg] = *(const half8*)(&pS[wid][l15][kg * 32 + l4 * 8]);
    half8 pf2 = *(const half8*)(&pS2[wid][l15][l4 * 8]);
#pragma unroll
    for (int nf = 0; nf < 4; ++nf) {
#pragma unroll
      for (int kg = 0; kg < 3; ++kg)
        o[nf] = __builtin_amdgcn_mfma_f32_16x16x32_f16(pfr[kg], vb[nf][kg], o[nf], 0, 0, 0);
      o[nf] = __builtin_amdgcn_mfma_f32_16x16x32_f16(pf2, vlb[nf], o[nf], 0, 0, 0);
    }

    // ---- store via per-wave transpose: 2x16B contiguous per lane
#pragma unroll
    for (int nf = 0; nf < 4; ++nf)
#pragma unroll
      for (int j = 0; j < 4; ++j)
        oesc[wid][l4 * 4 + j][nf * 16 + l15] = (f16)o[nf][j];
    asm volatile("s_waitcnt lgkmcnt(0)" ::: "memory");
    {
      const int rrow = lane >> 2;
      const int rcg  = lane & 3;
      half8 v0 = *(const half8*)(&oesc[wid][rrow][rcg * 16]);
      half8 v1 = *(const half8*)(&oesc[wid][rrow][rcg * 16 + 8]);
      asm volatile("" ::: "memory");
      f16* dst = AO + ((size_t)(bb * 96 + t0 + rrow) * 256 + hw) * 512 + h * 64 + rcg * 16;
      *(half8*)dst = v0;
      *(half8*)(dst + 8) = v1;
    }
  }
}

// ---------------------------------------------------------------------------
extern "C" void kernel_launch(void* const* d_in, const int* in_sizes, int n_in,
                              void* d_out, int out_size, void* d_ws, size_t ws_size,
                              hipStream_t stream) {
  (void)in_sizes; (void)n_in; (void)out_size;
  const float* x     = (const float*)d_in[0];
  const float* gamma = (const float*)d_in[1];
  const float* beta  = (const float*)d_in[2];
  const float* Wq    = (const float*)d_in[3];
  const float* Wk    = (const float*)d_in[4];
  const float* Wv    = (const float*)d_in[5];
  const float* Wkl   = (const float*)d_in[6];
  const float* Wvl   = (const float*)d_in[7];
  const float* Wo    = (const float*)d_in[8];
  const float* qb    = (const float*)d_in[9];
  float* out = (float*)d_out;

  char* ws = (char*)d_ws;
  size_t off = 0;
  auto alloc = [&](size_t bytes) -> void* {
    void* p = ws + off;
    off += (bytes + 255) & ~(size_t)255;
    return p;
  };
  f16* XN   = (f16*)alloc((size_t)MTOT * 512 * 2);
  f16* AO   = (f16*)alloc((size_t)MTOT * 512 * 2);
  f16* WQKV = (f16*)alloc((size_t)2560 * 512 * 2);
  f16* WOh  = (f16*)alloc((size_t)512 * 512 * 2);
  // chunking over n (512 total) to bound workspace; need cn*96 % 256 == 0
  int cn = 512;
  while (cn > 32 && off + (size_t)cn * 96 * 2560 * 2 + 256 > ws_size)
    cn >>= 1;
  f16* QKVc = (f16*)alloc((size_t)cn * 96 * 2560 * 2);

  wconv_kernel<<<5120, 256, 0, stream>>>(Wq, Wk, Wv, Wkl, Wvl, Wo, WQKV, WOh);
  ln_kernel<<<768, 256, 0, stream>>>(x, gamma, beta, XN);

  const int nch = 512 / cn;
  for (int c = 0; c < nch; ++c) {
    const int mtiles = (cn * 96) / 256;
    gemmA_kernel<<<mtiles * 10, 512, 0, stream>>>(XN + (size_t)c * cn * 96 * 512,
                                                  WQKV, QKVc, qb);
    attn_kernel<<<cn * 8, 192, 0, stream>>>(QKVc, AO, c * cn);
  }
  gemmO256_kernel<<<384, 512, 0, stream>>>(WOh, AO, out);
}